// Round 1
// baseline (1062.422 us; speedup 1.0000x reference)
//
#include <hip/hip_runtime.h>
#include <math.h>

// Problem constants (also derived from in_sizes at launch for robustness)
#define IN_DIM 1536
#define HID 512
#define MID 128
#define OUTC 5
#define HEADS 8
#define NEG_SLOPE 0.2f
#define BN_EPS 1e-5f

// ---------------------------------------------------------------------------
// CSR build: histogram -> single-block scan -> scatter
// ---------------------------------------------------------------------------
__global__ void hist_kernel(const int* __restrict__ ei, int* __restrict__ deg,
                            int ET, int E) {
    int e = blockIdx.x * blockDim.x + threadIdx.x;
    if (e >= ET) return;
    int dst = (e < E) ? ei[E + e] : (e - E);   // self-loop for e >= E
    atomicAdd(&deg[dst], 1);
}

__global__ __launch_bounds__(1024) void scan_kernel(const int* __restrict__ deg,
                                                    int* __restrict__ row_ptr,
                                                    int* __restrict__ cursor, int n) {
    __shared__ int partial[1024];
    int tid = threadIdx.x;
    int per = (n + 1023) / 1024;
    int base = tid * per;
    int s = 0;
    for (int i = 0; i < per; ++i) {
        int idx = base + i;
        if (idx < n) s += deg[idx];
    }
    partial[tid] = s;
    __syncthreads();
    // Hillis-Steele inclusive scan
    for (int off = 1; off < 1024; off <<= 1) {
        int v = (tid >= off) ? partial[tid - off] : 0;
        __syncthreads();
        partial[tid] += v;
        __syncthreads();
    }
    int prefix = (tid == 0) ? 0 : partial[tid - 1];
    for (int i = 0; i < per; ++i) {
        int idx = base + i;
        if (idx < n) {
            row_ptr[idx] = prefix;
            cursor[idx] = prefix;
            prefix += deg[idx];
        }
    }
    if (tid == 1023) row_ptr[n] = partial[1023];
}

__global__ void scatter_kernel(const int* __restrict__ ei, int* __restrict__ cursor,
                               int* __restrict__ csr_src, int ET, int E) {
    int e = blockIdx.x * blockDim.x + threadIdx.x;
    if (e >= ET) return;
    int src, dst;
    if (e < E) { src = ei[e]; dst = ei[E + e]; }
    else       { src = dst = e - E; }
    int slot = atomicAdd(&cursor[dst], 1);
    csr_src[slot] = src;
}

// ---------------------------------------------------------------------------
// fp32 tiled GEMM: C[M,N] = A[M,K] @ B[K,N].  N % 64 == 0, K % 16 == 0, M guarded.
// ---------------------------------------------------------------------------
#define BM 64
#define BN 64
#define BK 16
__global__ __launch_bounds__(256) void gemm_f32(const float* __restrict__ A,
                                                const float* __restrict__ B,
                                                float* __restrict__ C,
                                                int M, int N, int K) {
    __shared__ float As[BK][BM + 4];   // +4 pad: 16B-aligned rows, no write conflicts
    __shared__ float Bs[BK][BN];
    int tid = threadIdx.x;
    int tx = tid & 15;   // col group
    int ty = tid >> 4;   // row group
    int row0 = blockIdx.y * BM;
    int col0 = blockIdx.x * BN;

    int a_m = tid >> 4;    // 0..15
    int a_k = tid & 15;    // 0..15
    int b_k = tid >> 6;    // 0..3
    int b_n = tid & 63;    // 0..63

    float acc[4][4] = {};

    for (int k0 = 0; k0 < K; k0 += BK) {
#pragma unroll
        for (int i = 0; i < 4; ++i) {
            int m = a_m + 16 * i;
            int gr = row0 + m;
            As[a_k][m] = (gr < M) ? A[(size_t)gr * K + k0 + a_k] : 0.f;
        }
#pragma unroll
        for (int i = 0; i < 4; ++i) {
            int k = b_k + 4 * i;
            Bs[k][b_n] = B[(size_t)(k0 + k) * N + col0 + b_n];
        }
        __syncthreads();
#pragma unroll
        for (int k = 0; k < BK; ++k) {
            float4 av = *reinterpret_cast<const float4*>(&As[k][ty * 4]);
            float4 bv = *reinterpret_cast<const float4*>(&Bs[k][tx * 4]);
            float a[4] = {av.x, av.y, av.z, av.w};
            float b[4] = {bv.x, bv.y, bv.z, bv.w};
#pragma unroll
            for (int i = 0; i < 4; ++i)
#pragma unroll
                for (int j = 0; j < 4; ++j) acc[i][j] += a[i] * b[j];
        }
        __syncthreads();
    }
#pragma unroll
    for (int i = 0; i < 4; ++i) {
        int gr = row0 + ty * 4 + i;
        if (gr < M) {
            float4 v = make_float4(acc[i][0], acc[i][1], acc[i][2], acc[i][3]);
            *reinterpret_cast<float4*>(&C[(size_t)gr * N + col0 + tx * 4]) = v;
        }
    }
}

// ---------------------------------------------------------------------------
// Per-(node,head) alignment dots: al_s[n,h] = sum_c h[n,h,c]*a_src[h,c], same for dst
// ---------------------------------------------------------------------------
template <int H, int C>
__global__ void alsd_kernel(const float* __restrict__ hlin, const float* __restrict__ a_s,
                            const float* __restrict__ a_d, float* __restrict__ als,
                            float* __restrict__ ald, int n) {
    int t = blockIdx.x * blockDim.x + threadIdx.x;
    if (t >= n * H) return;
    int node = t / H, h = t % H;
    const float* row = hlin + (size_t)node * H * C + h * C;
    const float* asr = a_s + h * C;
    const float* adr = a_d + h * C;
    float ss = 0.f, sd = 0.f;
#pragma unroll 4
    for (int c = 0; c < C; ++c) {
        float v = row[c];
        ss += v * asr[c];
        sd += v * adr[c];
    }
    als[t] = ss;
    ald[t] = sd;
}

// ---------------------------------------------------------------------------
// Per-(dst,head) segment softmax over incoming edges: two-pass max / exp-sum.
// Writes per-edge-slot ex and per-(dst,head) reciprocal denom.
// ---------------------------------------------------------------------------
template <int H>
__global__ void attn_kernel(const float* __restrict__ als, const float* __restrict__ ald,
                            const int* __restrict__ row_ptr, const int* __restrict__ csr_src,
                            float* __restrict__ ex, float* __restrict__ rden, int n) {
    int t = blockIdx.x * blockDim.x + threadIdx.x;
    if (t >= n * H) return;
    int dst = t / H, h = t % H;
    int s0 = row_ptr[dst], s1 = row_ptr[dst + 1];
    float ad = ald[t];
    float m = -INFINITY;
    for (int j = s0; j < s1; ++j) {
        float e = als[csr_src[j] * H + h] + ad;
        e = (e >= 0.f) ? e : NEG_SLOPE * e;
        m = fmaxf(m, e);
    }
    float sum = 0.f;
    for (int j = s0; j < s1; ++j) {
        float e = als[csr_src[j] * H + h] + ad;
        e = (e >= 0.f) ? e : NEG_SLOPE * e;
        float x = __expf(e - m);
        ex[(size_t)j * H + h] = x;
        sum += x;
    }
    rden[t] = 1.0f / (sum + 1e-16f);
}

// ---------------------------------------------------------------------------
// Aggregation (one block per dst) fused with bias + ReLU + BN(eval).
// blockDim.x == F. h = f >> logc.
// ---------------------------------------------------------------------------
__global__ __launch_bounds__(512) void agg_bnrelu_kernel(
    const float* __restrict__ hlin, const float* __restrict__ ex,
    const float* __restrict__ rden, const int* __restrict__ row_ptr,
    const int* __restrict__ csr_src, const float* __restrict__ bias,
    const float* __restrict__ gamma, const float* __restrict__ beta,
    const float* __restrict__ mean, const float* __restrict__ var,
    float* __restrict__ out, int F, int logc, int H) {
    int dst = blockIdx.x;
    int f = threadIdx.x;
    int h = f >> logc;
    int s0 = row_ptr[dst], s1 = row_ptr[dst + 1];
    float rd = rden[dst * H + h];
    float acc = 0.f;
    for (int j = s0; j < s1; ++j) {
        int src = csr_src[j];                       // uniform -> scalar load
        float alpha = ex[(size_t)j * H + h] * rd;
        acc += alpha * hlin[(size_t)src * F + f];   // coalesced row gather
    }
    acc += bias[f];
    acc = fmaxf(acc, 0.f);
    acc = (acc - mean[f]) * rsqrtf(var[f] + BN_EPS) * gamma[f] + beta[f];
    out[(size_t)dst * F + f] = acc;
}

// ---------------------------------------------------------------------------
// Layer 3 linear: h3lin[n,5] = h2post[n,128] @ W3[128,5]
// ---------------------------------------------------------------------------
__global__ void layer3_lin_kernel(const float* __restrict__ h2, const float* __restrict__ W3,
                                  float* __restrict__ h3lin, int n) {
    int node = blockIdx.x * blockDim.x + threadIdx.x;
    if (node >= n) return;
    const float* row = h2 + (size_t)node * MID;
    float acc[OUTC] = {0.f, 0.f, 0.f, 0.f, 0.f};
    for (int k = 0; k < MID; ++k) {
        float x = row[k];
#pragma unroll
        for (int c = 0; c < OUTC; ++c) acc[c] += x * W3[k * OUTC + c];
    }
#pragma unroll
    for (int c = 0; c < OUTC; ++c) h3lin[(size_t)node * OUTC + c] = acc[c];
}

// ---------------------------------------------------------------------------
// Layer 3 aggregation + bias + log_softmax (one thread per dst, H=1, C=5)
// ---------------------------------------------------------------------------
__global__ void agg3_lsm_kernel(const float* __restrict__ h3lin, const float* __restrict__ ex,
                                const float* __restrict__ rden, const int* __restrict__ row_ptr,
                                const int* __restrict__ csr_src, const float* __restrict__ b3,
                                float* __restrict__ out, int n) {
    int dst = blockIdx.x * blockDim.x + threadIdx.x;
    if (dst >= n) return;
    int s0 = row_ptr[dst], s1 = row_ptr[dst + 1];
    float rd = rden[dst];
    float acc[OUTC] = {0.f, 0.f, 0.f, 0.f, 0.f};
    for (int j = s0; j < s1; ++j) {
        int src = csr_src[j];
        float a = ex[j] * rd;
#pragma unroll
        for (int c = 0; c < OUTC; ++c) acc[c] += a * h3lin[(size_t)src * OUTC + c];
    }
    float m = -INFINITY;
#pragma unroll
    for (int c = 0; c < OUTC; ++c) {
        acc[c] += b3[c];
        m = fmaxf(m, acc[c]);
    }
    float s = 0.f;
#pragma unroll
    for (int c = 0; c < OUTC; ++c) s += __expf(acc[c] - m);
    float lse = m + __logf(s);
#pragma unroll
    for (int c = 0; c < OUTC; ++c) out[(size_t)dst * OUTC + c] = acc[c] - lse;
}

// ---------------------------------------------------------------------------
extern "C" void kernel_launch(void* const* d_in, const int* in_sizes, int n_in,
                              void* d_out, int out_size, void* d_ws, size_t ws_size,
                              hipStream_t stream) {
    const float* x   = (const float*)d_in[0];
    const int*   ei  = (const int*)d_in[1];
    const float* W1  = (const float*)d_in[2];
    const float* as1 = (const float*)d_in[3];
    const float* ad1 = (const float*)d_in[4];
    const float* b1  = (const float*)d_in[5];
    const float* W2  = (const float*)d_in[6];
    const float* as2 = (const float*)d_in[7];
    const float* ad2 = (const float*)d_in[8];
    const float* b2  = (const float*)d_in[9];
    const float* W3  = (const float*)d_in[10];
    const float* as3 = (const float*)d_in[11];
    const float* ad3 = (const float*)d_in[12];
    const float* b3  = (const float*)d_in[13];
    const float* g1  = (const float*)d_in[14];
    const float* be1 = (const float*)d_in[15];
    const float* m1  = (const float*)d_in[16];
    const float* v1  = (const float*)d_in[17];
    const float* g2  = (const float*)d_in[18];
    const float* be2 = (const float*)d_in[19];
    const float* m2  = (const float*)d_in[20];
    const float* v2  = (const float*)d_in[21];

    const int N = in_sizes[0] / IN_DIM;      // 20000
    const int E = in_sizes[1] / 2;           // 320000
    const int ET = E + N;                    // with self-loops

    // Workspace carve-up (~96 MB)
    char* ws = (char*)d_ws;
    size_t off = 0;
    auto take = [&](size_t bytes) -> char* {
        char* p = ws + off;
        off += (bytes + 255) & ~(size_t)255;
        return p;
    };
    int* deg      = (int*)take((size_t)N * 4);
    int* row_ptr  = (int*)take((size_t)(N + 1) * 4);
    int* cursor   = (int*)take((size_t)N * 4);
    int* csr_src  = (int*)take((size_t)ET * 4);
    float* h1lin  = (float*)take((size_t)N * HID * 4);
    float* h1post = (float*)take((size_t)N * HID * 4);
    float* als    = (float*)take((size_t)N * HEADS * 4);
    float* ald    = (float*)take((size_t)N * HEADS * 4);
    float* exbuf  = (float*)take((size_t)ET * HEADS * 4);
    float* rden   = (float*)take((size_t)N * HEADS * 4);
    // aliases inside the dead h1lin region after layer-1 aggregation:
    float* h2lin  = h1lin;                    // N*128
    float* h2post = h1lin + (size_t)N * 128;  // N*128
    float* h3lin  = h1lin + (size_t)N * 256;  // N*5

    // ---- CSR build (shared by all 3 layers) ----
    hipMemsetAsync(deg, 0, (size_t)N * 4, stream);
    hist_kernel<<<(ET + 255) / 256, 256, 0, stream>>>(ei, deg, ET, E);
    scan_kernel<<<1, 1024, 0, stream>>>(deg, row_ptr, cursor, N);
    scatter_kernel<<<(ET + 255) / 256, 256, 0, stream>>>(ei, cursor, csr_src, ET, E);

    // ---- Layer 1: 1536 -> 8x64, ReLU, BN ----
    {
        dim3 grid(HID / BN, (N + BM - 1) / BM);
        gemm_f32<<<grid, 256, 0, stream>>>(x, W1, h1lin, N, HID, IN_DIM);
    }
    alsd_kernel<HEADS, 64><<<(N * HEADS + 255) / 256, 256, 0, stream>>>(h1lin, as1, ad1, als, ald, N);
    attn_kernel<HEADS><<<(N * HEADS + 255) / 256, 256, 0, stream>>>(als, ald, row_ptr, csr_src, exbuf, rden, N);
    agg_bnrelu_kernel<<<N, HID, 0, stream>>>(h1lin, exbuf, rden, row_ptr, csr_src,
                                             b1, g1, be1, m1, v1, h1post, HID, 6, HEADS);

    // ---- Layer 2: 512 -> 8x16, ReLU, BN ----
    {
        dim3 grid(MID / BN, (N + BM - 1) / BM);
        gemm_f32<<<grid, 256, 0, stream>>>(h1post, W2, h2lin, N, MID, HID);
    }
    alsd_kernel<HEADS, 16><<<(N * HEADS + 255) / 256, 256, 0, stream>>>(h2lin, as2, ad2, als, ald, N);
    attn_kernel<HEADS><<<(N * HEADS + 255) / 256, 256, 0, stream>>>(als, ald, row_ptr, csr_src, exbuf, rden, N);
    agg_bnrelu_kernel<<<N, MID, 0, stream>>>(h2lin, exbuf, rden, row_ptr, csr_src,
                                             b2, g2, be2, m2, v2, h2post, MID, 4, HEADS);

    // ---- Layer 3: 128 -> 1x5, log_softmax ----
    layer3_lin_kernel<<<(N + 255) / 256, 256, 0, stream>>>(h2post, W3, h3lin, N);
    alsd_kernel<1, OUTC><<<(N + 255) / 256, 256, 0, stream>>>(h3lin, as3, ad3, als, ald, N);
    attn_kernel<1><<<(N + 255) / 256, 256, 0, stream>>>(als, ald, row_ptr, csr_src, exbuf, rden, N);
    agg3_lsm_kernel<<<(N + 255) / 256, 256, 0, stream>>>(h3lin, exbuf, rden, row_ptr, csr_src,
                                                         b3, (float*)d_out, N);
}

// Round 2
// 704.153 us; speedup vs baseline: 1.5088x; 1.5088x over previous
//
#include <hip/hip_runtime.h>
#include <math.h>

#define IN_DIM 1536
#define HID 512
#define MID 128
#define OUTC 5
#define HEADS 8
#define NEG_SLOPE 0.2f
#define BN_EPS 1e-5f

typedef __attribute__((ext_vector_type(8))) short s16x8;
typedef __attribute__((ext_vector_type(4))) float fx4;

// ---------------------------------------------------------------------------
// CSR build: histogram -> single-block scan -> scatter
// ---------------------------------------------------------------------------
__global__ void hist_kernel(const int* __restrict__ ei, int* __restrict__ deg,
                            int ET, int E) {
    int e = blockIdx.x * blockDim.x + threadIdx.x;
    if (e >= ET) return;
    int dst = (e < E) ? ei[E + e] : (e - E);
    atomicAdd(&deg[dst], 1);
}

__global__ __launch_bounds__(1024) void scan_kernel(const int* __restrict__ deg,
                                                    int* __restrict__ row_ptr,
                                                    int* __restrict__ cursor, int n) {
    __shared__ int partial[1024];
    int tid = threadIdx.x;
    int per = (n + 1023) / 1024;
    int base = tid * per;
    int s = 0;
    for (int i = 0; i < per; ++i) {
        int idx = base + i;
        if (idx < n) s += deg[idx];
    }
    partial[tid] = s;
    __syncthreads();
    for (int off = 1; off < 1024; off <<= 1) {
        int v = (tid >= off) ? partial[tid - off] : 0;
        __syncthreads();
        partial[tid] += v;
        __syncthreads();
    }
    int prefix = (tid == 0) ? 0 : partial[tid - 1];
    for (int i = 0; i < per; ++i) {
        int idx = base + i;
        if (idx < n) {
            row_ptr[idx] = prefix;
            cursor[idx] = prefix;
            prefix += deg[idx];
        }
    }
    if (tid == 1023) row_ptr[n] = partial[1023];
}

__global__ void scatter_kernel(const int* __restrict__ ei, int* __restrict__ cursor,
                               int* __restrict__ csr_src, int ET, int E) {
    int e = blockIdx.x * blockDim.x + threadIdx.x;
    if (e >= ET) return;
    int src, dst;
    if (e < E) { src = ei[e]; dst = ei[E + e]; }
    else       { src = dst = e - E; }
    int slot = atomicAdd(&cursor[dst], 1);
    csr_src[slot] = src;
}

// ---------------------------------------------------------------------------
// Transpose + bf16 hi/lo split of weights: W[K][N] fp32 -> Th/Tl [N][K] bf16.
// hi = truncate(w) (top 16 bits); lo = truncate(w - hi). Residual ~2^-16 rel.
// ---------------------------------------------------------------------------
__global__ __launch_bounds__(256) void transpose_split(
    const float* __restrict__ W, unsigned short* __restrict__ Th,
    unsigned short* __restrict__ Tl, int K, int Nn) {
    __shared__ float tile[32][33];
    int kb = blockIdx.y * 32, nb = blockIdx.x * 32;
    int tx = threadIdx.x & 31, ty = threadIdx.x >> 5;   // 32 x 8
#pragma unroll
    for (int r = 0; r < 4; ++r)
        tile[ty + r * 8][tx] = W[(size_t)(kb + ty + r * 8) * Nn + nb + tx];
    __syncthreads();
#pragma unroll
    for (int r = 0; r < 4; ++r) {
        int n = ty + r * 8;
        float v = tile[tx][n];
        unsigned int u = __float_as_uint(v);
        unsigned short hi = (unsigned short)(u >> 16);
        float hif = __uint_as_float(u & 0xFFFF0000u);
        unsigned short lo = (unsigned short)(__float_as_uint(v - hif) >> 16);
        size_t o = (size_t)(nb + n) * K + kb + tx;
        Th[o] = hi;
        Tl[o] = lo;
    }
}

// ---------------------------------------------------------------------------
// Split 8 fp32 values into hi/lo bf16x8 fragments (truncation scheme).
// ---------------------------------------------------------------------------
__device__ __forceinline__ void split8(const float4& f0, const float4& f1,
                                       s16x8& hi, s16x8& lo) {
    float x[8] = {f0.x, f0.y, f0.z, f0.w, f1.x, f1.y, f1.z, f1.w};
    union { unsigned int u[4]; s16x8 s; } H, L;
#pragma unroll
    for (int p = 0; p < 4; ++p) {
        unsigned int u0 = __float_as_uint(x[2 * p]);
        unsigned int u1 = __float_as_uint(x[2 * p + 1]);
        unsigned int h0 = u0 & 0xFFFF0000u;
        unsigned int h1 = u1 & 0xFFFF0000u;
        H.u[p] = (u0 >> 16) | h1;
        float r0 = x[2 * p]     - __uint_as_float(h0);
        float r1 = x[2 * p + 1] - __uint_as_float(h1);
        L.u[p] = (__float_as_uint(r0) >> 16) | (__float_as_uint(r1) & 0xFFFF0000u);
    }
    hi = H.s;
    lo = L.s;
}

__device__ __forceinline__ void async_copy16(void* lds, const void* g) {
    __builtin_amdgcn_global_load_lds(
        (const __attribute__((address_space(1))) unsigned int*)g,
        (__attribute__((address_space(3))) unsigned int*)lds, 16, 0, 0);
}

// ---------------------------------------------------------------------------
// Split-bf16 MFMA GEMM: C[M][N] = A[M][K](fp32) @ B[K][N], with B given as
// pre-split transposed bf16 (Bh/Bl, layout [N][K]). A is split in-registers.
// C = Ah*Bh + Ah*Bl + Al*Bh (Al*Bl dropped, ~2^-16 relative).
// Tile 128x128, BK=32, 256 threads = 4 waves of 64x64 each.
// ---------------------------------------------------------------------------
__global__ __launch_bounds__(256) void gemm_split_mfma(
    const float* __restrict__ A, const unsigned short* __restrict__ Bh,
    const unsigned short* __restrict__ Bl, float* __restrict__ C,
    int M, int Arows, int N, int K) {
    __shared__ float Asf[128 * 32];            // 16 KB
    __shared__ unsigned short Bsh[128 * 32];   // 8 KB
    __shared__ unsigned short Bsl[128 * 32];   // 8 KB

    const int tid = threadIdx.x;
    const int lane = tid & 63;
    const int wv = tid >> 6;
    const int row0 = blockIdx.y * 128;
    const int nb0 = blockIdx.x * 128;
    const int col = lane & 15;
    const int quad = lane >> 4;
    const int m0 = (wv >> 1) * 64;
    const int n0 = (wv & 1) * 64;

    fx4 acc[4][4];
#pragma unroll
    for (int i = 0; i < 4; ++i)
#pragma unroll
        for (int j = 0; j < 4; ++j) acc[i][j] = (fx4){0.f, 0.f, 0.f, 0.f};

    // staging lane coords: A instr = 8 rows x 128B; B instr = 16 rows x 64B
    const int arow_l = lane >> 3, achk = lane & 7;
    const int brow_l = lane >> 2, bchk = lane & 3;

    for (int k0 = 0; k0 < K; k0 += 32) {
        // A: 16 1KB-instrs total, 4 per wave
#pragma unroll
        for (int h = 0; h < 4; ++h) {
            int s = wv * 4 + h;
            int gr = row0 + s * 8 + arow_l;
            if (gr >= Arows) gr = Arows - 1;   // clamp: avoid OOB, store-guarded
            const float* gp = A + (size_t)gr * K + k0 + achk * 4;
            async_copy16(&Asf[s * 8 * 32], gp);
        }
        // B hi/lo: 8+8 1KB-instrs total, 2+2 per wave
#pragma unroll
        for (int h = 0; h < 2; ++h) {
            int t = wv * 2 + h;
            int gn = nb0 + t * 16 + brow_l;
            size_t go = (size_t)gn * K + k0 + bchk * 8;
            async_copy16(&Bsh[t * 16 * 32], Bh + go);
            async_copy16(&Bsl[t * 16 * 32], Bl + go);
        }
        __syncthreads();

        s16x8 ah[4], al[4], bh[4], bl[4];
#pragma unroll
        for (int i = 0; i < 4; ++i) {
            const float* p = &Asf[(m0 + i * 16 + col) * 32 + quad * 8];
            float4 f0 = *(const float4*)p;
            float4 f1 = *(const float4*)(p + 4);
            split8(f0, f1, ah[i], al[i]);
            bh[i] = *(const s16x8*)&Bsh[(n0 + i * 16 + col) * 32 + quad * 8];
            bl[i] = *(const s16x8*)&Bsl[(n0 + i * 16 + col) * 32 + quad * 8];
        }
#pragma unroll
        for (int i = 0; i < 4; ++i)
#pragma unroll
            for (int j = 0; j < 4; ++j) {
                acc[i][j] = __builtin_amdgcn_mfma_f32_16x16x32_bf16(al[i], bh[j], acc[i][j], 0, 0, 0);
                acc[i][j] = __builtin_amdgcn_mfma_f32_16x16x32_bf16(ah[i], bl[j], acc[i][j], 0, 0, 0);
                acc[i][j] = __builtin_amdgcn_mfma_f32_16x16x32_bf16(ah[i], bh[j], acc[i][j], 0, 0, 0);
            }
        __syncthreads();
    }

    // C/D layout: col = lane&15, row = quad*4 + reg
#pragma unroll
    for (int i = 0; i < 4; ++i) {
        int gr0 = row0 + m0 + i * 16 + quad * 4;
#pragma unroll
        for (int j = 0; j < 4; ++j) {
            int gc = nb0 + n0 + j * 16 + col;
#pragma unroll
            for (int r = 0; r < 4; ++r) {
                int gr = gr0 + r;
                if (gr < M) C[(size_t)gr * N + gc] = acc[i][j][r];
            }
        }
    }
}

// ---------------------------------------------------------------------------
// Per-(node,head) alignment dots
// ---------------------------------------------------------------------------
template <int H, int C>
__global__ void alsd_kernel(const float* __restrict__ hlin, const float* __restrict__ a_s,
                            const float* __restrict__ a_d, float* __restrict__ als,
                            float* __restrict__ ald, int n) {
    int t = blockIdx.x * blockDim.x + threadIdx.x;
    if (t >= n * H) return;
    int node = t / H, h = t % H;
    const float* row = hlin + (size_t)node * H * C + h * C;
    const float* asr = a_s + h * C;
    const float* adr = a_d + h * C;
    float ss = 0.f, sd = 0.f;
#pragma unroll 4
    for (int c = 0; c < C; ++c) {
        float v = row[c];
        ss += v * asr[c];
        sd += v * adr[c];
    }
    als[t] = ss;
    ald[t] = sd;
}

// ---------------------------------------------------------------------------
// Segment softmax per (dst, head)
// ---------------------------------------------------------------------------
template <int H>
__global__ void attn_kernel(const float* __restrict__ als, const float* __restrict__ ald,
                            const int* __restrict__ row_ptr, const int* __restrict__ csr_src,
                            float* __restrict__ ex, float* __restrict__ rden, int n) {
    int t = blockIdx.x * blockDim.x + threadIdx.x;
    if (t >= n * H) return;
    int dst = t / H, h = t % H;
    int s0 = row_ptr[dst], s1 = row_ptr[dst + 1];
    float ad = ald[t];
    float m = -INFINITY;
    for (int j = s0; j < s1; ++j) {
        float e = als[csr_src[j] * H + h] + ad;
        e = (e >= 0.f) ? e : NEG_SLOPE * e;
        m = fmaxf(m, e);
    }
    float sum = 0.f;
    for (int j = s0; j < s1; ++j) {
        float e = als[csr_src[j] * H + h] + ad;
        e = (e >= 0.f) ? e : NEG_SLOPE * e;
        float x = __expf(e - m);
        ex[(size_t)j * H + h] = x;
        sum += x;
    }
    rden[t] = 1.0f / (sum + 1e-16f);
}

// ---------------------------------------------------------------------------
// Layer-1 aggregation (F=512), float4-vectorized, fused bias+ReLU+BN
// ---------------------------------------------------------------------------
__global__ __launch_bounds__(128) void agg1_kernel(
    const float* __restrict__ hlin, const float* __restrict__ ex,
    const float* __restrict__ rden, const int* __restrict__ row_ptr,
    const int* __restrict__ csr_src, const float* __restrict__ bias,
    const float* __restrict__ gamma, const float* __restrict__ beta,
    const float* __restrict__ mean, const float* __restrict__ var,
    float* __restrict__ out) {
    int dst = blockIdx.x;
    int f = threadIdx.x * 4;
    int h = f >> 6;
    int s0 = row_ptr[dst], s1 = row_ptr[dst + 1];
    float rd = rden[dst * HEADS + h];
    float ax = 0.f, ay = 0.f, az = 0.f, aw = 0.f;
    for (int j = s0; j < s1; ++j) {
        int src = csr_src[j];
        float a = ex[(size_t)j * HEADS + h] * rd;
        float4 v = *(const float4*)&hlin[(size_t)src * HID + f];
        ax += a * v.x; ay += a * v.y; az += a * v.z; aw += a * v.w;
    }
    float4 bi = *(const float4*)&bias[f];
    float4 gm = *(const float4*)&gamma[f];
    float4 bt = *(const float4*)&beta[f];
    float4 mn = *(const float4*)&mean[f];
    float4 vr = *(const float4*)&var[f];
    float4 o;
    o.x = (fmaxf(ax + bi.x, 0.f) - mn.x) * rsqrtf(vr.x + BN_EPS) * gm.x + bt.x;
    o.y = (fmaxf(ay + bi.y, 0.f) - mn.y) * rsqrtf(vr.y + BN_EPS) * gm.y + bt.y;
    o.z = (fmaxf(az + bi.z, 0.f) - mn.z) * rsqrtf(vr.z + BN_EPS) * gm.z + bt.z;
    o.w = (fmaxf(aw + bi.w, 0.f) - mn.w) * rsqrtf(vr.w + BN_EPS) * gm.w + bt.w;
    *(float4*)&out[(size_t)dst * HID + f] = o;
}

// ---------------------------------------------------------------------------
// Generic scalar aggregation (used for layer 2, F=128), fused bias+ReLU+BN
// ---------------------------------------------------------------------------
__global__ __launch_bounds__(512) void agg_bnrelu_kernel(
    const float* __restrict__ hlin, const float* __restrict__ ex,
    const float* __restrict__ rden, const int* __restrict__ row_ptr,
    const int* __restrict__ csr_src, const float* __restrict__ bias,
    const float* __restrict__ gamma, const float* __restrict__ beta,
    const float* __restrict__ mean, const float* __restrict__ var,
    float* __restrict__ out, int F, int logc, int H) {
    int dst = blockIdx.x;
    int f = threadIdx.x;
    int h = f >> logc;
    int s0 = row_ptr[dst], s1 = row_ptr[dst + 1];
    float rd = rden[dst * H + h];
    float acc = 0.f;
    for (int j = s0; j < s1; ++j) {
        int src = csr_src[j];
        float alpha = ex[(size_t)j * H + h] * rd;
        acc += alpha * hlin[(size_t)src * F + f];
    }
    acc += bias[f];
    acc = fmaxf(acc, 0.f);
    acc = (acc - mean[f]) * rsqrtf(var[f] + BN_EPS) * gamma[f] + beta[f];
    out[(size_t)dst * F + f] = acc;
}

// ---------------------------------------------------------------------------
// Layer 3 linear: h3lin[n,5] = h2post[n,128] @ W3[128,5]
// ---------------------------------------------------------------------------
__global__ void layer3_lin_kernel(const float* __restrict__ h2, const float* __restrict__ W3,
                                  float* __restrict__ h3lin, int n) {
    int node = blockIdx.x * blockDim.x + threadIdx.x;
    if (node >= n) return;
    const float* row = h2 + (size_t)node * MID;
    float acc[OUTC] = {0.f, 0.f, 0.f, 0.f, 0.f};
    for (int k = 0; k < MID; ++k) {
        float x = row[k];
#pragma unroll
        for (int c = 0; c < OUTC; ++c) acc[c] += x * W3[k * OUTC + c];
    }
#pragma unroll
    for (int c = 0; c < OUTC; ++c) h3lin[(size_t)node * OUTC + c] = acc[c];
}

// ---------------------------------------------------------------------------
// Layer 3 aggregation + bias + log_softmax
// ---------------------------------------------------------------------------
__global__ void agg3_lsm_kernel(const float* __restrict__ h3lin, const float* __restrict__ ex,
                                const float* __restrict__ rden, const int* __restrict__ row_ptr,
                                const int* __restrict__ csr_src, const float* __restrict__ b3,
                                float* __restrict__ out, int n) {
    int dst = blockIdx.x * blockDim.x + threadIdx.x;
    if (dst >= n) return;
    int s0 = row_ptr[dst], s1 = row_ptr[dst + 1];
    float rd = rden[dst];
    float acc[OUTC] = {0.f, 0.f, 0.f, 0.f, 0.f};
    for (int j = s0; j < s1; ++j) {
        int src = csr_src[j];
        float a = ex[j] * rd;
#pragma unroll
        for (int c = 0; c < OUTC; ++c) acc[c] += a * h3lin[(size_t)src * OUTC + c];
    }
    float m = -INFINITY;
#pragma unroll
    for (int c = 0; c < OUTC; ++c) {
        acc[c] += b3[c];
        m = fmaxf(m, acc[c]);
    }
    float s = 0.f;
#pragma unroll
    for (int c = 0; c < OUTC; ++c) s += __expf(acc[c] - m);
    float lse = m + __logf(s);
#pragma unroll
    for (int c = 0; c < OUTC; ++c) out[(size_t)dst * OUTC + c] = acc[c] - lse;
}

// ---------------------------------------------------------------------------
extern "C" void kernel_launch(void* const* d_in, const int* in_sizes, int n_in,
                              void* d_out, int out_size, void* d_ws, size_t ws_size,
                              hipStream_t stream) {
    const float* x   = (const float*)d_in[0];
    const int*   ei  = (const int*)d_in[1];
    const float* W1  = (const float*)d_in[2];
    const float* as1 = (const float*)d_in[3];
    const float* ad1 = (const float*)d_in[4];
    const float* b1  = (const float*)d_in[5];
    const float* W2  = (const float*)d_in[6];
    const float* as2 = (const float*)d_in[7];
    const float* ad2 = (const float*)d_in[8];
    const float* b2  = (const float*)d_in[9];
    const float* W3  = (const float*)d_in[10];
    const float* as3 = (const float*)d_in[11];
    const float* ad3 = (const float*)d_in[12];
    const float* b3  = (const float*)d_in[13];
    const float* g1  = (const float*)d_in[14];
    const float* be1 = (const float*)d_in[15];
    const float* m1  = (const float*)d_in[16];
    const float* v1  = (const float*)d_in[17];
    const float* g2  = (const float*)d_in[18];
    const float* be2 = (const float*)d_in[19];
    const float* m2  = (const float*)d_in[20];
    const float* v2  = (const float*)d_in[21];

    const int N = in_sizes[0] / IN_DIM;       // 20000
    const int E = in_sizes[1] / 2;            // 320000
    const int ET = E + N;
    const int MBLK = (N + 127) / 128;         // 157
    const int Mpad = MBLK * 128;              // 20096

    char* ws = (char*)d_ws;
    size_t off = 0;
    auto take = [&](size_t bytes) -> char* {
        char* p = ws + off;
        off += (bytes + 255) & ~(size_t)255;
        return p;
    };
    int* deg      = (int*)take((size_t)N * 4);
    int* row_ptr  = (int*)take((size_t)(N + 1) * 4);
    int* cursor   = (int*)take((size_t)N * 4);
    int* csr_src  = (int*)take((size_t)ET * 4);
    unsigned short* W1Th = (unsigned short*)take((size_t)HID * IN_DIM * 2);
    unsigned short* W1Tl = (unsigned short*)take((size_t)HID * IN_DIM * 2);
    unsigned short* W2Th = (unsigned short*)take((size_t)MID * HID * 2);
    unsigned short* W2Tl = (unsigned short*)take((size_t)MID * HID * 2);
    float* h1lin  = (float*)take((size_t)N * HID * 4);
    float* h1post = (float*)take((size_t)Mpad * HID * 4);
    float* als    = (float*)take((size_t)N * HEADS * 4);
    float* ald    = (float*)take((size_t)N * HEADS * 4);
    float* exbuf  = (float*)take((size_t)ET * HEADS * 4);
    float* rden   = (float*)take((size_t)N * HEADS * 4);
    // dead-region aliases after layer-1 aggregation:
    float* h2lin  = h1lin;                    // N*128
    float* h2post = h1lin + (size_t)N * 128;  // N*128
    float* h3lin  = h1lin + (size_t)N * 256;  // N*5

    // ---- CSR build + weight prepasses ----
    hipMemsetAsync(deg, 0, (size_t)N * 4, stream);
    hist_kernel<<<(ET + 255) / 256, 256, 0, stream>>>(ei, deg, ET, E);
    scan_kernel<<<1, 1024, 0, stream>>>(deg, row_ptr, cursor, N);
    scatter_kernel<<<(ET + 255) / 256, 256, 0, stream>>>(ei, cursor, csr_src, ET, E);
    transpose_split<<<dim3(HID / 32, IN_DIM / 32), 256, 0, stream>>>(W1, W1Th, W1Tl, IN_DIM, HID);
    transpose_split<<<dim3(MID / 32, HID / 32), 256, 0, stream>>>(W2, W2Th, W2Tl, HID, MID);

    // ---- Layer 1: 1536 -> 8x64, ReLU, BN ----
    gemm_split_mfma<<<dim3(HID / 128, MBLK), 256, 0, stream>>>(
        x, W1Th, W1Tl, h1lin, N, N, HID, IN_DIM);
    alsd_kernel<HEADS, 64><<<(N * HEADS + 255) / 256, 256, 0, stream>>>(h1lin, as1, ad1, als, ald, N);
    attn_kernel<HEADS><<<(N * HEADS + 255) / 256, 256, 0, stream>>>(als, ald, row_ptr, csr_src, exbuf, rden, N);
    agg1_kernel<<<N, 128, 0, stream>>>(h1lin, exbuf, rden, row_ptr, csr_src,
                                       b1, g1, be1, m1, v1, h1post);

    // ---- Layer 2: 512 -> 8x16, ReLU, BN ----
    gemm_split_mfma<<<dim3(MID / 128, MBLK), 256, 0, stream>>>(
        h1post, W2Th, W2Tl, h2lin, N, Mpad, MID, HID);
    alsd_kernel<HEADS, 16><<<(N * HEADS + 255) / 256, 256, 0, stream>>>(h2lin, as2, ad2, als, ald, N);
    attn_kernel<HEADS><<<(N * HEADS + 255) / 256, 256, 0, stream>>>(als, ald, row_ptr, csr_src, exbuf, rden, N);
    agg_bnrelu_kernel<<<N, MID, 0, stream>>>(h2lin, exbuf, rden, row_ptr, csr_src,
                                             b2, g2, be2, m2, v2, h2post, MID, 4, HEADS);

    // ---- Layer 3: 128 -> 1x5, log_softmax ----
    layer3_lin_kernel<<<(N + 255) / 256, 256, 0, stream>>>(h2post, W3, h3lin, N);
    alsd_kernel<1, OUTC><<<(N + 255) / 256, 256, 0, stream>>>(h3lin, as3, ad3, als, ald, N);
    attn_kernel<1><<<(N + 255) / 256, 256, 0, stream>>>(als, ald, row_ptr, csr_src, exbuf, rden, N);
    agg3_lsm_kernel<<<(N + 255) / 256, 256, 0, stream>>>(h3lin, exbuf, rden, row_ptr, csr_src,
                                                         b3, (float*)d_out, N);
}

// Round 3
// 563.278 us; speedup vs baseline: 1.8861x; 1.2501x over previous
//
#include <hip/hip_runtime.h>
#include <math.h>

#define IN_DIM 1536
#define HID 512
#define MID 128
#define OUTC 5
#define HEADS 8
#define NEG_SLOPE 0.2f
#define BN_EPS 1e-5f

typedef __attribute__((ext_vector_type(8))) short s16x8;
typedef __attribute__((ext_vector_type(4))) float fx4;

__device__ __forceinline__ unsigned short bf16_rne(float f) {
    unsigned int u = __float_as_uint(f);
    u += 0x7fffu + ((u >> 16) & 1u);
    return (unsigned short)(u >> 16);
}

__device__ __forceinline__ void async_copy16(void* lds, const void* g) {
    __builtin_amdgcn_global_load_lds(
        (const __attribute__((address_space(1))) unsigned int*)g,
        (__attribute__((address_space(3))) unsigned int*)lds, 16, 0, 0);
}

// ---------------------------------------------------------------------------
// CSR build: histogram -> single-block scan -> scatter
// ---------------------------------------------------------------------------
__global__ void hist_kernel(const int* __restrict__ ei, int* __restrict__ deg,
                            int ET, int E) {
    int e = blockIdx.x * blockDim.x + threadIdx.x;
    if (e >= ET) return;
    int dst = (e < E) ? ei[E + e] : (e - E);
    atomicAdd(&deg[dst], 1);
}

__global__ __launch_bounds__(1024) void scan_kernel(const int* __restrict__ deg,
                                                    int* __restrict__ row_ptr,
                                                    int* __restrict__ cursor, int n) {
    __shared__ int partial[1024];
    int tid = threadIdx.x;
    int per = (n + 1023) / 1024;
    int base = tid * per;
    int s = 0;
    for (int i = 0; i < per; ++i) {
        int idx = base + i;
        if (idx < n) s += deg[idx];
    }
    partial[tid] = s;
    __syncthreads();
    for (int off = 1; off < 1024; off <<= 1) {
        int v = (tid >= off) ? partial[tid - off] : 0;
        __syncthreads();
        partial[tid] += v;
        __syncthreads();
    }
    int prefix = (tid == 0) ? 0 : partial[tid - 1];
    for (int i = 0; i < per; ++i) {
        int idx = base + i;
        if (idx < n) {
            row_ptr[idx] = prefix;
            cursor[idx] = prefix;
            prefix += deg[idx];
        }
    }
    if (tid == 1023) row_ptr[n] = partial[1023];
}

__global__ void scatter_kernel(const int* __restrict__ ei, int* __restrict__ cursor,
                               int* __restrict__ csr_src, int ET, int E) {
    int e = blockIdx.x * blockDim.x + threadIdx.x;
    if (e >= ET) return;
    int src, dst;
    if (e < E) { src = ei[e]; dst = ei[E + e]; }
    else       { src = dst = e - E; }
    int slot = atomicAdd(&cursor[dst], 1);
    csr_src[slot] = src;
}

// ---------------------------------------------------------------------------
// x fp32 -> bf16 (RNE), 4 elems/thread
// ---------------------------------------------------------------------------
__global__ void cvt_bf16_kernel(const float* __restrict__ in,
                                unsigned short* __restrict__ out, int n4) {
    int i = blockIdx.x * blockDim.x + threadIdx.x;
    if (i >= n4) return;
    float4 v = ((const float4*)in)[i];
    ushort4 o;
    o.x = bf16_rne(v.x); o.y = bf16_rne(v.y);
    o.z = bf16_rne(v.z); o.w = bf16_rne(v.w);
    ((ushort4*)out)[i] = o;
}

// ---------------------------------------------------------------------------
// Transpose + bf16 hi/lo split of weights (RNE): W[K][N] -> Th/Tl [N][K]
// ---------------------------------------------------------------------------
__global__ __launch_bounds__(256) void transpose_split(
    const float* __restrict__ W, unsigned short* __restrict__ Th,
    unsigned short* __restrict__ Tl, int K, int Nn) {
    __shared__ float tile[32][33];
    int kb = blockIdx.y * 32, nb = blockIdx.x * 32;
    int tx = threadIdx.x & 31, ty = threadIdx.x >> 5;
#pragma unroll
    for (int r = 0; r < 4; ++r)
        tile[ty + r * 8][tx] = W[(size_t)(kb + ty + r * 8) * Nn + nb + tx];
    __syncthreads();
#pragma unroll
    for (int r = 0; r < 4; ++r) {
        int n = ty + r * 8;
        float v = tile[tx][n];
        unsigned short hi = bf16_rne(v);
        float hif = __uint_as_float((unsigned int)hi << 16);
        unsigned short lo = bf16_rne(v - hif);
        size_t o = (size_t)(nb + n) * K + kb + tx;
        Th[o] = hi;
        Tl[o] = lo;
    }
}

// ---------------------------------------------------------------------------
// bf16 MFMA GEMM, 2-term: C = Ah*(Bh+Bl), A plain bf16 [Arows][K],
// B pre-split transposed bf16 [N][K]. Tile MTx128, BK=32, 256 thr = 4 waves.
// bf16 rows are 64B so the wave's ds_read_b128 covers each 1KB subtile
// bijectively -> minimal LDS cycles, no swizzle needed.
// ---------------------------------------------------------------------------
template <int MT>   // 128 or 64
__global__ __launch_bounds__(256) void gemm_bf16(
    const unsigned short* __restrict__ Ah, const unsigned short* __restrict__ Bh,
    const unsigned short* __restrict__ Bl, float* __restrict__ C,
    int M, int Arows, int N, int K) {
    constexpr int WM = MT / 2;     // rows per wave
    constexpr int MI = WM / 16;    // m-frags per wave
    constexpr int AI = MT / 64;    // A staging instrs per wave
    __shared__ unsigned short Ash[MT * 32];
    __shared__ unsigned short Bsh[128 * 32];
    __shared__ unsigned short Bsl[128 * 32];

    const int tid = threadIdx.x;
    const int lane = tid & 63;
    const int wv = tid >> 6;
    const int row0 = blockIdx.y * MT;
    const int nb0 = blockIdx.x * 128;
    const int col = lane & 15;
    const int quad = lane >> 4;
    const int m0 = (wv >> 1) * WM;
    const int n0 = (wv & 1) * 64;
    const int row_l = lane >> 2;   // 16 rows x 64B per staging instr
    const int chk = lane & 3;

    fx4 acc[MI][4];
#pragma unroll
    for (int i = 0; i < MI; ++i)
#pragma unroll
        for (int j = 0; j < 4; ++j) acc[i][j] = (fx4){0.f, 0.f, 0.f, 0.f};

    for (int k0 = 0; k0 < K; k0 += 32) {
#pragma unroll
        for (int h = 0; h < AI; ++h) {
            int t = wv * AI + h;
            int gr = row0 + t * 16 + row_l;
            if (gr >= Arows) gr = Arows - 1;
            async_copy16(&Ash[t * 512], Ah + (size_t)gr * K + k0 + chk * 8);
        }
#pragma unroll
        for (int h = 0; h < 2; ++h) {
            int t = wv * 2 + h;
            int gn = nb0 + t * 16 + row_l;
            size_t go = (size_t)gn * K + k0 + chk * 8;
            async_copy16(&Bsh[t * 512], Bh + go);
            async_copy16(&Bsl[t * 512], Bl + go);
        }
        __syncthreads();

        s16x8 a[MI], bh4[4], bl4[4];
#pragma unroll
        for (int i = 0; i < MI; ++i)
            a[i] = *(const s16x8*)&Ash[(m0 + i * 16 + col) * 32 + quad * 8];
#pragma unroll
        for (int j = 0; j < 4; ++j) {
            int rb = (n0 + j * 16 + col) * 32 + quad * 8;
            bh4[j] = *(const s16x8*)&Bsh[rb];
            bl4[j] = *(const s16x8*)&Bsl[rb];
        }
#pragma unroll
        for (int i = 0; i < MI; ++i)
#pragma unroll
            for (int j = 0; j < 4; ++j) {
                acc[i][j] = __builtin_amdgcn_mfma_f32_16x16x32_bf16(a[i], bl4[j], acc[i][j], 0, 0, 0);
                acc[i][j] = __builtin_amdgcn_mfma_f32_16x16x32_bf16(a[i], bh4[j], acc[i][j], 0, 0, 0);
            }
        __syncthreads();
    }

    // C/D layout: col = lane&15, row = quad*4 + reg
#pragma unroll
    for (int i = 0; i < MI; ++i) {
        int gr0 = row0 + m0 + i * 16 + quad * 4;
#pragma unroll
        for (int j = 0; j < 4; ++j) {
            int gc = nb0 + n0 + j * 16 + col;
#pragma unroll
            for (int r = 0; r < 4; ++r) {
                int gr = gr0 + r;
                if (gr < M) C[(size_t)gr * N + gc] = acc[i][j][r];
            }
        }
    }
}

// ---------------------------------------------------------------------------
// Per-(node,head) alignment dots
// ---------------------------------------------------------------------------
template <int H, int C>
__global__ void alsd_kernel(const float* __restrict__ hlin, const float* __restrict__ a_s,
                            const float* __restrict__ a_d, float* __restrict__ als,
                            float* __restrict__ ald, int n) {
    int t = blockIdx.x * blockDim.x + threadIdx.x;
    if (t >= n * H) return;
    int node = t / H, h = t % H;
    const float* row = hlin + (size_t)node * H * C + h * C;
    const float* asr = a_s + h * C;
    const float* adr = a_d + h * C;
    float ss = 0.f, sd = 0.f;
#pragma unroll 4
    for (int c = 0; c < C; ++c) {
        float v = row[c];
        ss += v * asr[c];
        sd += v * adr[c];
    }
    als[t] = ss;
    ald[t] = sd;
}

// ---------------------------------------------------------------------------
// Fused attention-softmax + aggregation + bias + ReLU + BN.
// One block (128 thr) per dst node. Per 16-edge chunk: compute phase
// (lanes = (edge, head)) computes ex into LDS (exp without max-subtract:
// |e| << 88, mathematically identical alphas); aggregate phase accumulates
// weighted features + denominator in-register; normalize at the end.
// SPLIT=true writes bf16 output (feeds next GEMM); else fp32.
// ---------------------------------------------------------------------------
template <int F, int VEC, bool SPLIT>
__global__ __launch_bounds__(128) void agg_fused_kernel(
    const float* __restrict__ hlin, const float* __restrict__ als,
    const float* __restrict__ ald, const int* __restrict__ row_ptr,
    const int* __restrict__ csr_src, const float* __restrict__ bias,
    const float* __restrict__ gamma, const float* __restrict__ beta,
    const float* __restrict__ mean, const float* __restrict__ var,
    float* __restrict__ outf, unsigned short* __restrict__ outh) {
    int dst = blockIdx.x;
    int tid = threadIdx.x;
    int f0 = tid * VEC;
    int h = tid >> 4;              // holds for (512,VEC4,C64) and (128,VEC1,C16)
    __shared__ float exs[16][8];
    __shared__ int srcs[16];
    int s0 = row_ptr[dst], s1 = row_ptr[dst + 1];
    int cj = tid >> 3, ch = tid & 7;
    float ald_c = ald[dst * HEADS + ch];
    float acc[VEC];
#pragma unroll
    for (int v = 0; v < VEC; ++v) acc[v] = 0.f;
    float den = 0.f;

    for (int base = s0; base < s1; base += 16) {
        int take = min(16, s1 - base);
        if (cj < take) {
            int src = csr_src[base + cj];
            if (ch == 0) srcs[cj] = src;
            float e = als[src * HEADS + ch] + ald_c;
            e = (e >= 0.f) ? e : NEG_SLOPE * e;
            exs[cj][ch] = __expf(e);
        }
        __syncthreads();
        for (int jj = 0; jj < take; ++jj) {
            int src = srcs[jj];
            float a = exs[jj][h];
            den += a;
            const float* rp = &hlin[(size_t)src * F + f0];
            if (VEC == 4) {
                float4 v4 = *(const float4*)rp;
                acc[0] += a * v4.x; acc[1] += a * v4.y;
                acc[2] += a * v4.z; acc[3] += a * v4.w;
            } else {
                acc[0] += a * rp[0];
            }
        }
        __syncthreads();
    }

    float rd = 1.f / (den + 1e-16f);
    float res[VEC];
#pragma unroll
    for (int v = 0; v < VEC; ++v) {
        int f = f0 + v;
        float val = acc[v] * rd + bias[f];
        val = fmaxf(val, 0.f);
        val = (val - mean[f]) * rsqrtf(var[f] + BN_EPS) * gamma[f] + beta[f];
        res[v] = val;
    }
    if (SPLIT) {
        if (VEC == 4) {
            ushort4 o;
            o.x = bf16_rne(res[0]); o.y = bf16_rne(res[1]);
            o.z = bf16_rne(res[2]); o.w = bf16_rne(res[3]);
            *(ushort4*)&outh[(size_t)dst * F + f0] = o;
        } else {
            outh[(size_t)dst * F + f0] = bf16_rne(res[0]);
        }
    } else {
        if (VEC == 4) {
            *(float4*)&outf[(size_t)dst * F + f0] =
                make_float4(res[0], res[1], res[2], res[3]);
        } else {
            outf[(size_t)dst * F + f0] = res[0];
        }
    }
}

// ---------------------------------------------------------------------------
// Layer 3 linear fused with alignment dots:
// h3lin[n,5] = h2post[n,128] @ W3[128,5]; als3/ald3 = h3lin . a_{src,dst}
// ---------------------------------------------------------------------------
__global__ void layer3_lin_kernel(const float* __restrict__ h2, const float* __restrict__ W3,
                                  const float* __restrict__ as3, const float* __restrict__ ad3,
                                  float* __restrict__ h3lin, float* __restrict__ als,
                                  float* __restrict__ ald, int n) {
    int node = blockIdx.x * blockDim.x + threadIdx.x;
    if (node >= n) return;
    const float* row = h2 + (size_t)node * MID;
    float acc[OUTC] = {0.f, 0.f, 0.f, 0.f, 0.f};
    for (int k = 0; k < MID; ++k) {
        float x = row[k];
#pragma unroll
        for (int c = 0; c < OUTC; ++c) acc[c] += x * W3[k * OUTC + c];
    }
    float ss = 0.f, sd = 0.f;
#pragma unroll
    for (int c = 0; c < OUTC; ++c) {
        h3lin[(size_t)node * OUTC + c] = acc[c];
        ss += acc[c] * as3[c];
        sd += acc[c] * ad3[c];
    }
    als[node] = ss;
    ald[node] = sd;
}

// ---------------------------------------------------------------------------
// Layer 3: fused single-pass softmax + aggregation + bias + log_softmax
// ---------------------------------------------------------------------------
__global__ void agg3_lsm_kernel(const float* __restrict__ h3lin, const float* __restrict__ als,
                                const float* __restrict__ ald, const int* __restrict__ row_ptr,
                                const int* __restrict__ csr_src, const float* __restrict__ b3,
                                float* __restrict__ out, int n) {
    int dst = blockIdx.x * blockDim.x + threadIdx.x;
    if (dst >= n) return;
    int s0 = row_ptr[dst], s1 = row_ptr[dst + 1];
    float ad = ald[dst];
    float den = 0.f;
    float acc[OUTC] = {0.f, 0.f, 0.f, 0.f, 0.f};
    for (int j = s0; j < s1; ++j) {
        int src = csr_src[j];
        float e = als[src] + ad;
        e = (e >= 0.f) ? e : NEG_SLOPE * e;
        float x = __expf(e);
        den += x;
#pragma unroll
        for (int c = 0; c < OUTC; ++c) acc[c] += x * h3lin[(size_t)src * OUTC + c];
    }
    float rd = 1.f / (den + 1e-16f);
    float m = -INFINITY;
#pragma unroll
    for (int c = 0; c < OUTC; ++c) {
        acc[c] = acc[c] * rd + b3[c];
        m = fmaxf(m, acc[c]);
    }
    float s = 0.f;
#pragma unroll
    for (int c = 0; c < OUTC; ++c) s += __expf(acc[c] - m);
    float lse = m + __logf(s);
#pragma unroll
    for (int c = 0; c < OUTC; ++c) out[(size_t)dst * OUTC + c] = acc[c] - lse;
}

// ---------------------------------------------------------------------------
extern "C" void kernel_launch(void* const* d_in, const int* in_sizes, int n_in,
                              void* d_out, int out_size, void* d_ws, size_t ws_size,
                              hipStream_t stream) {
    const float* x   = (const float*)d_in[0];
    const int*   ei  = (const int*)d_in[1];
    const float* W1  = (const float*)d_in[2];
    const float* as1 = (const float*)d_in[3];
    const float* ad1 = (const float*)d_in[4];
    const float* b1  = (const float*)d_in[5];
    const float* W2  = (const float*)d_in[6];
    const float* as2 = (const float*)d_in[7];
    const float* ad2 = (const float*)d_in[8];
    const float* b2  = (const float*)d_in[9];
    const float* W3  = (const float*)d_in[10];
    const float* as3 = (const float*)d_in[11];
    const float* ad3 = (const float*)d_in[12];
    const float* b3  = (const float*)d_in[13];
    const float* g1  = (const float*)d_in[14];
    const float* be1 = (const float*)d_in[15];
    const float* m1  = (const float*)d_in[16];
    const float* v1  = (const float*)d_in[17];
    const float* g2  = (const float*)d_in[18];
    const float* be2 = (const float*)d_in[19];
    const float* m2  = (const float*)d_in[20];
    const float* v2  = (const float*)d_in[21];

    const int N = in_sizes[0] / IN_DIM;       // 20000
    const int E = in_sizes[1] / 2;            // 320000
    const int ET = E + N;
    const int MBLK1 = (N + 127) / 128;        // 157
    const int MBLK2 = (N + 63) / 64;          // 313

    char* ws = (char*)d_ws;
    size_t off = 0;
    auto take = [&](size_t bytes) -> char* {
        char* p = ws + off;
        off += (bytes + 255) & ~(size_t)255;
        return p;
    };
    int* deg      = (int*)take((size_t)N * 4);
    int* row_ptr  = (int*)take((size_t)(N + 1) * 4);
    int* cursor   = (int*)take((size_t)N * 4);
    int* csr_src  = (int*)take((size_t)ET * 4);
    unsigned short* W1h = (unsigned short*)take((size_t)HID * IN_DIM * 2);
    unsigned short* W1l = (unsigned short*)take((size_t)HID * IN_DIM * 2);
    unsigned short* W2h = (unsigned short*)take((size_t)MID * HID * 2);
    unsigned short* W2l = (unsigned short*)take((size_t)MID * HID * 2);
    // big region: xh during layer 1, then reused for h1h/h2lin/h2post/h3lin
    char* bigreg = take((size_t)N * IN_DIM * 2);       // 61.44 MB
    unsigned short* xh = (unsigned short*)bigreg;
    float* h1lin  = (float*)take((size_t)N * HID * 4); // 40.96 MB
    float* als    = (float*)take((size_t)N * HEADS * 4);
    float* ald    = (float*)take((size_t)N * HEADS * 4);
    // aliases into bigreg (xh dead after GEMM1):
    unsigned short* h1h = (unsigned short*)bigreg;                     // N*512 bf16
    float* h2lin  = (float*)(bigreg + (size_t)N * HID * 2);            // N*128 f32
    float* h2post = (float*)(bigreg + (size_t)N * HID * 2 + (size_t)N * MID * 4);
    float* h3lin  = (float*)(bigreg + (size_t)N * HID * 2 + (size_t)N * MID * 8);

    // ---- CSR build + weight prep + x->bf16 ----
    hipMemsetAsync(deg, 0, (size_t)N * 4, stream);
    hist_kernel<<<(ET + 255) / 256, 256, 0, stream>>>(ei, deg, ET, E);
    scan_kernel<<<1, 1024, 0, stream>>>(deg, row_ptr, cursor, N);
    scatter_kernel<<<(ET + 255) / 256, 256, 0, stream>>>(ei, cursor, csr_src, ET, E);
    transpose_split<<<dim3(HID / 32, IN_DIM / 32), 256, 0, stream>>>(W1, W1h, W1l, IN_DIM, HID);
    transpose_split<<<dim3(MID / 32, HID / 32), 256, 0, stream>>>(W2, W2h, W2l, HID, MID);
    {
        int n4 = N * IN_DIM / 4;
        cvt_bf16_kernel<<<(n4 + 255) / 256, 256, 0, stream>>>(x, xh, n4);
    }

    // ---- Layer 1: 1536 -> 8x64, ReLU, BN ----
    gemm_bf16<128><<<dim3(HID / 128, MBLK1), 256, 0, stream>>>(
        xh, W1h, W1l, h1lin, N, N, HID, IN_DIM);
    alsd_kernel<HEADS, 64><<<(N * HEADS + 255) / 256, 256, 0, stream>>>(h1lin, as1, ad1, als, ald, N);
    agg_fused_kernel<HID, 4, true><<<N, 128, 0, stream>>>(
        h1lin, als, ald, row_ptr, csr_src, b1, g1, be1, m1, v1, nullptr, h1h);

    // ---- Layer 2: 512 -> 8x16, ReLU, BN ----
    gemm_bf16<64><<<dim3(MID / 128, MBLK2), 256, 0, stream>>>(
        h1h, W2h, W2l, h2lin, N, N, MID, HID);
    alsd_kernel<HEADS, 16><<<(N * HEADS + 255) / 256, 256, 0, stream>>>(h2lin, as2, ad2, als, ald, N);
    agg_fused_kernel<MID, 1, false><<<N, 128, 0, stream>>>(
        h2lin, als, ald, row_ptr, csr_src, b2, g2, be2, m2, v2, h2post, nullptr);

    // ---- Layer 3: 128 -> 1x5, log_softmax ----
    layer3_lin_kernel<<<(N + 255) / 256, 256, 0, stream>>>(
        h2post, W3, as3, ad3, h3lin, als, ald, N);
    agg3_lsm_kernel<<<(N + 255) / 256, 256, 0, stream>>>(
        h3lin, als, ald, row_ptr, csr_src, b3, (float*)d_out, N);
}

// Round 4
// 507.352 us; speedup vs baseline: 2.0941x; 1.1102x over previous
//
#include <hip/hip_runtime.h>
#include <math.h>

#define IN_DIM 1536
#define HID 512
#define MID 128
#define OUTC 5
#define HEADS 8
#define NEG_SLOPE 0.2f
#define BN_EPS 1e-5f

typedef __attribute__((ext_vector_type(8))) short s16x8;
typedef __attribute__((ext_vector_type(4))) float fx4;

__device__ __forceinline__ unsigned short bf16_rne(float f) {
    unsigned int u = __float_as_uint(f);
    u += 0x7fffu + ((u >> 16) & 1u);
    return (unsigned short)(u >> 16);
}
__device__ __forceinline__ float bf16_to_f32(unsigned short u) {
    return __uint_as_float((unsigned int)u << 16);
}

__device__ __forceinline__ void async_copy16(void* lds, const void* g) {
    __builtin_amdgcn_global_load_lds(
        (const __attribute__((address_space(1))) unsigned int*)g,
        (__attribute__((address_space(3))) unsigned int*)lds, 16, 0, 0);
}

// ---------------------------------------------------------------------------
// CSR build: histogram -> single-block scan -> scatter
// ---------------------------------------------------------------------------
__global__ void hist_kernel(const int* __restrict__ ei, int* __restrict__ deg,
                            int ET, int E) {
    int e = blockIdx.x * blockDim.x + threadIdx.x;
    if (e >= ET) return;
    int dst = (e < E) ? ei[E + e] : (e - E);
    atomicAdd(&deg[dst], 1);
}

__global__ __launch_bounds__(1024) void scan_kernel(const int* __restrict__ deg,
                                                    int* __restrict__ row_ptr,
                                                    int* __restrict__ cursor, int n) {
    __shared__ int partial[1024];
    int tid = threadIdx.x;
    int per = (n + 1023) / 1024;
    int base = tid * per;
    int s = 0;
    for (int i = 0; i < per; ++i) {
        int idx = base + i;
        if (idx < n) s += deg[idx];
    }
    partial[tid] = s;
    __syncthreads();
    for (int off = 1; off < 1024; off <<= 1) {
        int v = (tid >= off) ? partial[tid - off] : 0;
        __syncthreads();
        partial[tid] += v;
        __syncthreads();
    }
    int prefix = (tid == 0) ? 0 : partial[tid - 1];
    for (int i = 0; i < per; ++i) {
        int idx = base + i;
        if (idx < n) {
            row_ptr[idx] = prefix;
            cursor[idx] = prefix;
            prefix += deg[idx];
        }
    }
    if (tid == 1023) row_ptr[n] = partial[1023];
}

__global__ void scatter_kernel(const int* __restrict__ ei, int* __restrict__ cursor,
                               int* __restrict__ csr_src, int ET, int E) {
    int e = blockIdx.x * blockDim.x + threadIdx.x;
    if (e >= ET) return;
    int src, dst;
    if (e < E) { src = ei[e]; dst = ei[E + e]; }
    else       { src = dst = e - E; }
    int slot = atomicAdd(&cursor[dst], 1);
    csr_src[slot] = src;
}

// ---------------------------------------------------------------------------
// x fp32 -> bf16 (RNE), 4 elems/thread
// ---------------------------------------------------------------------------
__global__ void cvt_bf16_kernel(const float* __restrict__ in,
                                unsigned short* __restrict__ out, int n4) {
    int i = blockIdx.x * blockDim.x + threadIdx.x;
    if (i >= n4) return;
    float4 v = ((const float4*)in)[i];
    ushort4 o;
    o.x = bf16_rne(v.x); o.y = bf16_rne(v.y);
    o.z = bf16_rne(v.z); o.w = bf16_rne(v.w);
    ((ushort4*)out)[i] = o;
}

// ---------------------------------------------------------------------------
// Transpose + bf16 hi/lo split of weights (RNE): W[K][N] -> Th/Tl [N][K]
// ---------------------------------------------------------------------------
__global__ __launch_bounds__(256) void transpose_split(
    const float* __restrict__ W, unsigned short* __restrict__ Th,
    unsigned short* __restrict__ Tl, int K, int Nn) {
    __shared__ float tile[32][33];
    int kb = blockIdx.y * 32, nb = blockIdx.x * 32;
    int tx = threadIdx.x & 31, ty = threadIdx.x >> 5;
#pragma unroll
    for (int r = 0; r < 4; ++r)
        tile[ty + r * 8][tx] = W[(size_t)(kb + ty + r * 8) * Nn + nb + tx];
    __syncthreads();
#pragma unroll
    for (int r = 0; r < 4; ++r) {
        int n = ty + r * 8;
        float v = tile[tx][n];
        unsigned short hi = bf16_rne(v);
        float hif = __uint_as_float((unsigned int)hi << 16);
        unsigned short lo = bf16_rne(v - hif);
        size_t o = (size_t)(nb + n) * K + kb + tx;
        Th[o] = hi;
        Tl[o] = lo;
    }
}

// ---------------------------------------------------------------------------
// bf16 MFMA GEMM, 2-term on B: C = A*(Bh+Bl). A bf16 [Arows][K],
// B pre-split transposed bf16 [N][K]. Tile MTx128, BK=32, 256 thr = 4 waves.
// OUTB=true: epilogue writes bf16 (halves downstream gather bytes).
// ---------------------------------------------------------------------------
template <int MT, bool OUTB>
__global__ __launch_bounds__(256) void gemm_bf16(
    const unsigned short* __restrict__ Ah, const unsigned short* __restrict__ Bh,
    const unsigned short* __restrict__ Bl, float* __restrict__ C,
    unsigned short* __restrict__ Cb, int M, int Arows, int N, int K) {
    constexpr int WM = MT / 2;
    constexpr int MI = WM / 16;
    constexpr int AI = MT / 64;
    __shared__ unsigned short Ash[MT * 32];
    __shared__ unsigned short Bsh[128 * 32];
    __shared__ unsigned short Bsl[128 * 32];

    const int tid = threadIdx.x;
    const int lane = tid & 63;
    const int wv = tid >> 6;
    const int row0 = blockIdx.y * MT;
    const int nb0 = blockIdx.x * 128;
    const int col = lane & 15;
    const int quad = lane >> 4;
    const int m0 = (wv >> 1) * WM;
    const int n0 = (wv & 1) * 64;
    const int row_l = lane >> 2;
    const int chk = lane & 3;

    fx4 acc[MI][4];
#pragma unroll
    for (int i = 0; i < MI; ++i)
#pragma unroll
        for (int j = 0; j < 4; ++j) acc[i][j] = (fx4){0.f, 0.f, 0.f, 0.f};

    for (int k0 = 0; k0 < K; k0 += 32) {
#pragma unroll
        for (int h = 0; h < AI; ++h) {
            int t = wv * AI + h;
            int gr = row0 + t * 16 + row_l;
            if (gr >= Arows) gr = Arows - 1;
            async_copy16(&Ash[t * 512], Ah + (size_t)gr * K + k0 + chk * 8);
        }
#pragma unroll
        for (int h = 0; h < 2; ++h) {
            int t = wv * 2 + h;
            int gn = nb0 + t * 16 + row_l;
            size_t go = (size_t)gn * K + k0 + chk * 8;
            async_copy16(&Bsh[t * 512], Bh + go);
            async_copy16(&Bsl[t * 512], Bl + go);
        }
        __syncthreads();

        s16x8 a[MI], bh4[4], bl4[4];
#pragma unroll
        for (int i = 0; i < MI; ++i)
            a[i] = *(const s16x8*)&Ash[(m0 + i * 16 + col) * 32 + quad * 8];
#pragma unroll
        for (int j = 0; j < 4; ++j) {
            int rb = (n0 + j * 16 + col) * 32 + quad * 8;
            bh4[j] = *(const s16x8*)&Bsh[rb];
            bl4[j] = *(const s16x8*)&Bsl[rb];
        }
#pragma unroll
        for (int i = 0; i < MI; ++i)
#pragma unroll
            for (int j = 0; j < 4; ++j) {
                acc[i][j] = __builtin_amdgcn_mfma_f32_16x16x32_bf16(a[i], bl4[j], acc[i][j], 0, 0, 0);
                acc[i][j] = __builtin_amdgcn_mfma_f32_16x16x32_bf16(a[i], bh4[j], acc[i][j], 0, 0, 0);
            }
        __syncthreads();
    }

    // C/D layout: col = lane&15, row = quad*4 + reg
#pragma unroll
    for (int i = 0; i < MI; ++i) {
        int gr0 = row0 + m0 + i * 16 + quad * 4;
#pragma unroll
        for (int j = 0; j < 4; ++j) {
            int gc = nb0 + n0 + j * 16 + col;
#pragma unroll
            for (int r = 0; r < 4; ++r) {
                int gr = gr0 + r;
                if (gr < M) {
                    if (OUTB) Cb[(size_t)gr * N + gc] = bf16_rne(acc[i][j][r]);
                    else      C[(size_t)gr * N + gc] = acc[i][j][r];
                }
            }
        }
    }
}

// ---------------------------------------------------------------------------
// Per-(node,head) alignment dots, bf16 feature input
// ---------------------------------------------------------------------------
template <int H, int C>
__global__ void alsd_kernel(const unsigned short* __restrict__ hlin,
                            const float* __restrict__ a_s,
                            const float* __restrict__ a_d, float* __restrict__ als,
                            float* __restrict__ ald, int n) {
    int t = blockIdx.x * blockDim.x + threadIdx.x;
    if (t >= n * H) return;
    int node = t / H, h = t % H;
    const unsigned short* row = hlin + (size_t)node * H * C + h * C;
    const float* asr = a_s + h * C;
    const float* adr = a_d + h * C;
    float ss = 0.f, sd = 0.f;
#pragma unroll
    for (int c0 = 0; c0 < C; c0 += 4) {
        ushort4 u = *(const ushort4*)&row[c0];
        float v0 = bf16_to_f32(u.x), v1 = bf16_to_f32(u.y);
        float v2 = bf16_to_f32(u.z), v3 = bf16_to_f32(u.w);
        ss += v0 * asr[c0] + v1 * asr[c0 + 1] + v2 * asr[c0 + 2] + v3 * asr[c0 + 3];
        sd += v0 * adr[c0] + v1 * adr[c0 + 1] + v2 * adr[c0 + 2] + v3 * adr[c0 + 3];
    }
    als[t] = ss;
    ald[t] = sd;
}

// ---------------------------------------------------------------------------
// Fused attention-softmax + aggregation + bias + ReLU + BN, bf16 gather.
// One block (128 thr) per dst. exp without max-subtract (|e| << 88; alphas
// mathematically identical). SPLIT=true -> bf16 out, else fp32.
// ---------------------------------------------------------------------------
template <int F, int VEC, bool SPLIT>
__global__ __launch_bounds__(128) void agg_fused_kernel(
    const unsigned short* __restrict__ hlin, const float* __restrict__ als,
    const float* __restrict__ ald, const int* __restrict__ row_ptr,
    const int* __restrict__ csr_src, const float* __restrict__ bias,
    const float* __restrict__ gamma, const float* __restrict__ beta,
    const float* __restrict__ mean, const float* __restrict__ var,
    float* __restrict__ outf, unsigned short* __restrict__ outh) {
    int dst = blockIdx.x;
    int tid = threadIdx.x;
    int f0 = tid * VEC;
    int h = tid >> 4;              // (512,VEC4,C64) and (128,VEC1,C16)
    __shared__ float exs[16][8];
    __shared__ int srcs[16];
    int s0 = row_ptr[dst], s1 = row_ptr[dst + 1];
    int cj = tid >> 3, ch = tid & 7;
    float ald_c = ald[dst * HEADS + ch];
    float acc[VEC];
#pragma unroll
    for (int v = 0; v < VEC; ++v) acc[v] = 0.f;
    float den = 0.f;

    for (int base = s0; base < s1; base += 16) {
        int take = min(16, s1 - base);
        if (cj < take) {
            int src = csr_src[base + cj];
            if (ch == 0) srcs[cj] = src;
            float e = als[src * HEADS + ch] + ald_c;
            e = (e >= 0.f) ? e : NEG_SLOPE * e;
            exs[cj][ch] = __expf(e);
        }
        __syncthreads();
        for (int jj = 0; jj < take; ++jj) {
            int src = srcs[jj];
            float a = exs[jj][h];
            den += a;
            const unsigned short* rp = &hlin[(size_t)src * F + f0];
            if (VEC == 4) {
                ushort4 u = *(const ushort4*)rp;
                acc[0] += a * bf16_to_f32(u.x);
                acc[1] += a * bf16_to_f32(u.y);
                acc[2] += a * bf16_to_f32(u.z);
                acc[3] += a * bf16_to_f32(u.w);
            } else {
                acc[0] += a * bf16_to_f32(rp[0]);
            }
        }
        __syncthreads();
    }

    float rd = 1.f / (den + 1e-16f);
    float res[VEC];
#pragma unroll
    for (int v = 0; v < VEC; ++v) {
        int f = f0 + v;
        float val = acc[v] * rd + bias[f];
        val = fmaxf(val, 0.f);
        val = (val - mean[f]) * rsqrtf(var[f] + BN_EPS) * gamma[f] + beta[f];
        res[v] = val;
    }
    if (SPLIT) {
        if (VEC == 4) {
            ushort4 o;
            o.x = bf16_rne(res[0]); o.y = bf16_rne(res[1]);
            o.z = bf16_rne(res[2]); o.w = bf16_rne(res[3]);
            *(ushort4*)&outh[(size_t)dst * F + f0] = o;
        } else {
            outh[(size_t)dst * F + f0] = bf16_rne(res[0]);
        }
    } else {
        if (VEC == 4) {
            *(float4*)&outf[(size_t)dst * F + f0] =
                make_float4(res[0], res[1], res[2], res[3]);
        } else {
            outf[(size_t)dst * F + f0] = res[0];
        }
    }
}

// ---------------------------------------------------------------------------
// Layer 3 linear fused with alignment dots (fp32 input from agg2)
// ---------------------------------------------------------------------------
__global__ void layer3_lin_kernel(const float* __restrict__ h2, const float* __restrict__ W3,
                                  const float* __restrict__ as3, const float* __restrict__ ad3,
                                  float* __restrict__ h3lin, float* __restrict__ als,
                                  float* __restrict__ ald, int n) {
    int node = blockIdx.x * blockDim.x + threadIdx.x;
    if (node >= n) return;
    const float* row = h2 + (size_t)node * MID;
    float acc[OUTC] = {0.f, 0.f, 0.f, 0.f, 0.f};
    for (int k = 0; k < MID; ++k) {
        float x = row[k];
#pragma unroll
        for (int c = 0; c < OUTC; ++c) acc[c] += x * W3[k * OUTC + c];
    }
    float ss = 0.f, sd = 0.f;
#pragma unroll
    for (int c = 0; c < OUTC; ++c) {
        h3lin[(size_t)node * OUTC + c] = acc[c];
        ss += acc[c] * as3[c];
        sd += acc[c] * ad3[c];
    }
    als[node] = ss;
    ald[node] = sd;
}

// ---------------------------------------------------------------------------
// Layer 3: fused single-pass softmax + aggregation + bias + log_softmax
// ---------------------------------------------------------------------------
__global__ void agg3_lsm_kernel(const float* __restrict__ h3lin, const float* __restrict__ als,
                                const float* __restrict__ ald, const int* __restrict__ row_ptr,
                                const int* __restrict__ csr_src, const float* __restrict__ b3,
                                float* __restrict__ out, int n) {
    int dst = blockIdx.x * blockDim.x + threadIdx.x;
    if (dst >= n) return;
    int s0 = row_ptr[dst], s1 = row_ptr[dst + 1];
    float ad = ald[dst];
    float den = 0.f;
    float acc[OUTC] = {0.f, 0.f, 0.f, 0.f, 0.f};
    for (int j = s0; j < s1; ++j) {
        int src = csr_src[j];
        float e = als[src] + ad;
        e = (e >= 0.f) ? e : NEG_SLOPE * e;
        float x = __expf(e);
        den += x;
#pragma unroll
        for (int c = 0; c < OUTC; ++c) acc[c] += x * h3lin[(size_t)src * OUTC + c];
    }
    float rd = 1.f / (den + 1e-16f);
    float m = -INFINITY;
#pragma unroll
    for (int c = 0; c < OUTC; ++c) {
        acc[c] = acc[c] * rd + b3[c];
        m = fmaxf(m, acc[c]);
    }
    float s = 0.f;
#pragma unroll
    for (int c = 0; c < OUTC; ++c) s += __expf(acc[c] - m);
    float lse = m + __logf(s);
#pragma unroll
    for (int c = 0; c < OUTC; ++c) out[(size_t)dst * OUTC + c] = acc[c] - lse;
}

// ---------------------------------------------------------------------------
extern "C" void kernel_launch(void* const* d_in, const int* in_sizes, int n_in,
                              void* d_out, int out_size, void* d_ws, size_t ws_size,
                              hipStream_t stream) {
    const float* x   = (const float*)d_in[0];
    const int*   ei  = (const int*)d_in[1];
    const float* W1  = (const float*)d_in[2];
    const float* as1 = (const float*)d_in[3];
    const float* ad1 = (const float*)d_in[4];
    const float* b1  = (const float*)d_in[5];
    const float* W2  = (const float*)d_in[6];
    const float* as2 = (const float*)d_in[7];
    const float* ad2 = (const float*)d_in[8];
    const float* b2  = (const float*)d_in[9];
    const float* W3  = (const float*)d_in[10];
    const float* as3 = (const float*)d_in[11];
    const float* ad3 = (const float*)d_in[12];
    const float* b3  = (const float*)d_in[13];
    const float* g1  = (const float*)d_in[14];
    const float* be1 = (const float*)d_in[15];
    const float* m1  = (const float*)d_in[16];
    const float* v1  = (const float*)d_in[17];
    const float* g2  = (const float*)d_in[18];
    const float* be2 = (const float*)d_in[19];
    const float* m2  = (const float*)d_in[20];
    const float* v2  = (const float*)d_in[21];

    const int N = in_sizes[0] / IN_DIM;       // 20000
    const int E = in_sizes[1] / 2;            // 320000
    const int ET = E + N;
    const int MBLK1 = (N + 127) / 128;        // 157
    const int MBLK2 = (N + 63) / 64;          // 313

    char* ws = (char*)d_ws;
    size_t off = 0;
    auto take = [&](size_t bytes) -> char* {
        char* p = ws + off;
        off += (bytes + 255) & ~(size_t)255;
        return p;
    };
    int* deg      = (int*)take((size_t)N * 4);
    int* row_ptr  = (int*)take((size_t)(N + 1) * 4);
    int* cursor   = (int*)take((size_t)N * 4);
    int* csr_src  = (int*)take((size_t)ET * 4);
    unsigned short* W1h = (unsigned short*)take((size_t)HID * IN_DIM * 2);
    unsigned short* W1l = (unsigned short*)take((size_t)HID * IN_DIM * 2);
    unsigned short* W2h = (unsigned short*)take((size_t)MID * HID * 2);
    unsigned short* W2l = (unsigned short*)take((size_t)MID * HID * 2);
    // big region: xh during layer 1, then reused (xh dead after GEMM1)
    char* bigreg = take((size_t)N * IN_DIM * 2);             // 61.44 MB
    unsigned short* xh = (unsigned short*)bigreg;
    unsigned short* h1lin = (unsigned short*)take((size_t)N * HID * 2);  // bf16
    float* als    = (float*)take((size_t)N * HEADS * 4);
    float* ald    = (float*)take((size_t)N * HEADS * 4);
    // aliases into bigreg:
    unsigned short* h1h   = (unsigned short*)bigreg;                         // N*512 bf16
    unsigned short* h2lin = (unsigned short*)(bigreg + (size_t)N * HID * 2); // N*128 bf16
    float* h2post = (float*)(bigreg + (size_t)N * HID * 2 + (size_t)N * MID * 2);
    float* h3lin  = (float*)(bigreg + (size_t)N * HID * 2 + (size_t)N * MID * 2
                             + (size_t)N * MID * 4);

    // ---- CSR build + weight prep + x->bf16 ----
    hipMemsetAsync(deg, 0, (size_t)N * 4, stream);
    hist_kernel<<<(ET + 255) / 256, 256, 0, stream>>>(ei, deg, ET, E);
    scan_kernel<<<1, 1024, 0, stream>>>(deg, row_ptr, cursor, N);
    scatter_kernel<<<(ET + 255) / 256, 256, 0, stream>>>(ei, cursor, csr_src, ET, E);
    transpose_split<<<dim3(HID / 32, IN_DIM / 32), 256, 0, stream>>>(W1, W1h, W1l, IN_DIM, HID);
    transpose_split<<<dim3(MID / 32, HID / 32), 256, 0, stream>>>(W2, W2h, W2l, HID, MID);
    {
        int n4 = N * IN_DIM / 4;
        cvt_bf16_kernel<<<(n4 + 255) / 256, 256, 0, stream>>>(x, xh, n4);
    }

    // ---- Layer 1: 1536 -> 8x64, ReLU, BN ----
    gemm_bf16<128, true><<<dim3(HID / 128, MBLK1), 256, 0, stream>>>(
        xh, W1h, W1l, nullptr, h1lin, N, N, HID, IN_DIM);
    alsd_kernel<HEADS, 64><<<(N * HEADS + 255) / 256, 256, 0, stream>>>(h1lin, as1, ad1, als, ald, N);
    agg_fused_kernel<HID, 4, true><<<N, 128, 0, stream>>>(
        h1lin, als, ald, row_ptr, csr_src, b1, g1, be1, m1, v1, nullptr, h1h);

    // ---- Layer 2: 512 -> 8x16, ReLU, BN ----
    gemm_bf16<64, true><<<dim3(MID / 128, MBLK2), 256, 0, stream>>>(
        h1h, W2h, W2l, nullptr, h2lin, N, N, MID, HID);
    alsd_kernel<HEADS, 16><<<(N * HEADS + 255) / 256, 256, 0, stream>>>(h2lin, as2, ad2, als, ald, N);
    agg_fused_kernel<MID, 1, false><<<N, 128, 0, stream>>>(
        h2lin, als, ald, row_ptr, csr_src, b2, g2, be2, m2, v2, h2post, nullptr);

    // ---- Layer 3: 128 -> 1x5, log_softmax ----
    layer3_lin_kernel<<<(N + 255) / 256, 256, 0, stream>>>(
        h2post, W3, as3, ad3, h3lin, als, ald, N);
    agg3_lsm_kernel<<<(N + 255) / 256, 256, 0, stream>>>(
        h3lin, als, ald, row_ptr, csr_src, b3, (float*)d_out, N);
}

// Round 5
// 492.662 us; speedup vs baseline: 2.1565x; 1.0298x over previous
//
#include <hip/hip_runtime.h>
#include <math.h>

#define IN_DIM 1536
#define HID 512
#define MID 128
#define OUTC 5
#define HEADS 8
#define NEG_SLOPE 0.2f
#define BN_EPS 1e-5f

typedef __attribute__((ext_vector_type(8))) short s16x8;
typedef __attribute__((ext_vector_type(4))) float fx4;

__device__ __forceinline__ unsigned short bf16_rne(float f) {
    unsigned int u = __float_as_uint(f);
    u += 0x7fffu + ((u >> 16) & 1u);
    return (unsigned short)(u >> 16);
}
__device__ __forceinline__ float bf16_to_f32(unsigned short u) {
    return __uint_as_float((unsigned int)u << 16);
}

__device__ __forceinline__ void async_copy16(void* lds, const void* g) {
    __builtin_amdgcn_global_load_lds(
        (const __attribute__((address_space(1))) unsigned int*)g,
        (__attribute__((address_space(3))) unsigned int*)lds, 16, 0, 0);
}

// truncate 8 f32 -> bf16x8 (round-toward-zero on mantissa; bias ~2^-9,
// negligible vs existing 0.0156 absmax — R2 used same trunc, same absmax)
__device__ __forceinline__ s16x8 trunc8(float4 f0, float4 f1) {
    union { unsigned int u[4]; s16x8 s; } r;
    r.u[0] = (__float_as_uint(f0.x) >> 16) | (__float_as_uint(f0.y) & 0xFFFF0000u);
    r.u[1] = (__float_as_uint(f0.z) >> 16) | (__float_as_uint(f0.w) & 0xFFFF0000u);
    r.u[2] = (__float_as_uint(f1.x) >> 16) | (__float_as_uint(f1.y) & 0xFFFF0000u);
    r.u[3] = (__float_as_uint(f1.z) >> 16) | (__float_as_uint(f1.w) & 0xFFFF0000u);
    return r.s;
}

// ---------------------------------------------------------------------------
// CSR build: histogram -> single-block scan -> scatter
// ---------------------------------------------------------------------------
__global__ void hist_kernel(const int* __restrict__ ei, int* __restrict__ deg,
                            int ET, int E) {
    int e = blockIdx.x * blockDim.x + threadIdx.x;
    if (e >= ET) return;
    int dst = (e < E) ? ei[E + e] : (e - E);
    atomicAdd(&deg[dst], 1);
}

__global__ __launch_bounds__(1024) void scan_kernel(const int* __restrict__ deg,
                                                    int* __restrict__ row_ptr,
                                                    int* __restrict__ cursor, int n) {
    __shared__ int partial[1024];
    int tid = threadIdx.x;
    int per = (n + 1023) / 1024;
    int base = tid * per;
    int s = 0;
    for (int i = 0; i < per; ++i) {
        int idx = base + i;
        if (idx < n) s += deg[idx];
    }
    partial[tid] = s;
    __syncthreads();
    for (int off = 1; off < 1024; off <<= 1) {
        int v = (tid >= off) ? partial[tid - off] : 0;
        __syncthreads();
        partial[tid] += v;
        __syncthreads();
    }
    int prefix = (tid == 0) ? 0 : partial[tid - 1];
    for (int i = 0; i < per; ++i) {
        int idx = base + i;
        if (idx < n) {
            row_ptr[idx] = prefix;
            cursor[idx] = prefix;
            prefix += deg[idx];
        }
    }
    if (tid == 1023) row_ptr[n] = partial[1023];
}

__global__ void scatter_kernel(const int* __restrict__ ei, int* __restrict__ cursor,
                               int* __restrict__ csr_src, int ET, int E) {
    int e = blockIdx.x * blockDim.x + threadIdx.x;
    if (e >= ET) return;
    int src, dst;
    if (e < E) { src = ei[e]; dst = ei[E + e]; }
    else       { src = dst = e - E; }
    int slot = atomicAdd(&cursor[dst], 1);
    csr_src[slot] = src;
}

// ---------------------------------------------------------------------------
// Transpose + bf16 split of weights (RNE): W[K][N] -> Th (and Tl if WLO) [N][K]
// ---------------------------------------------------------------------------
template <bool WLO>
__global__ __launch_bounds__(256) void transpose_split(
    const float* __restrict__ W, unsigned short* __restrict__ Th,
    unsigned short* __restrict__ Tl, int K, int Nn) {
    __shared__ float tile[32][33];
    int kb = blockIdx.y * 32, nb = blockIdx.x * 32;
    int tx = threadIdx.x & 31, ty = threadIdx.x >> 5;
#pragma unroll
    for (int r = 0; r < 4; ++r)
        tile[ty + r * 8][tx] = W[(size_t)(kb + ty + r * 8) * Nn + nb + tx];
    __syncthreads();
#pragma unroll
    for (int r = 0; r < 4; ++r) {
        int n = ty + r * 8;
        float v = tile[tx][n];
        unsigned short hi = bf16_rne(v);
        size_t o = (size_t)(nb + n) * K + kb + tx;
        Th[o] = hi;
        if (WLO) {
            float hif = __uint_as_float((unsigned int)hi << 16);
            Tl[o] = bf16_rne(v - hif);
        }
    }
}

// ---------------------------------------------------------------------------
// GEMM1: C[M][N]=A@W, A fp32 [M][K] staged directly to LDS (XOR-swizzled) and
// truncated to bf16 in-register; B single-term bf16 [N][K]. Tile 128x128,
// BK=32, 256 thr = 4 waves of 64x64. XCD-aware block swizzle: the 4 N-blocks
// sharing A-rows get block ids 8 apart -> same XCD -> A fetched once per XCD.
// LDS swizzles (slot holds chunk slot^f(row)) make fragment reads 2-way max.
// ---------------------------------------------------------------------------
__global__ __launch_bounds__(256) void gemm1_kernel(
    const float* __restrict__ A, const unsigned short* __restrict__ Bh,
    unsigned short* __restrict__ Cb, int M, int N, int K, int MBLK) {
    int b = blockIdx.x;
    int xm = (b & 7) + 8 * (b >> 5);   // m-block
    int ym = (b >> 3) & 3;             // n-block
    if (xm >= MBLK) return;

    __shared__ float Asf[128 * 32];            // 16 KB, rows 128 B
    __shared__ unsigned short Bsh[128 * 32];   //  8 KB, rows 64 B

    const int tid = threadIdx.x;
    const int lane = tid & 63;
    const int wv = tid >> 6;
    const int row0 = xm * 128;
    const int nb0 = ym * 128;
    const int col = lane & 15;
    const int quad = lane >> 4;
    const int m0 = (wv >> 1) * 64;
    const int n0 = (wv & 1) * 64;

    // A staging: 1KB instr = 8 rows x 128B; lane: row=l>>3, slot=l&7,
    // fetched global chunk = slot ^ (row&7)
    const int a_row = lane >> 3;
    const int a_chunk = (lane & 7) ^ a_row;
    // B staging: 1KB instr = 16 rows x 64B; lane: row=l>>2, slot=l&3,
    // fetched global chunk = slot ^ ((row>>1)&3)
    const int b_row = lane >> 2;
    const int b_chunk = (lane & 3) ^ ((lane >> 3) & 3);

    fx4 acc[4][4];
#pragma unroll
    for (int i = 0; i < 4; ++i)
#pragma unroll
        for (int j = 0; j < 4; ++j) acc[i][j] = (fx4){0.f, 0.f, 0.f, 0.f};

    const int swA0 = (2 * quad) ^ (col & 7);
    const int swA1 = (2 * quad + 1) ^ (col & 7);
    const int swB = quad ^ ((col >> 1) & 3);

    for (int k0 = 0; k0 < K; k0 += 32) {
#pragma unroll
        for (int h = 0; h < 4; ++h) {
            int t = wv * 4 + h;
            int gr = row0 + t * 8 + a_row;
            if (gr >= M) gr = M - 1;
            async_copy16(&Asf[t * 256], A + (size_t)gr * K + k0 + a_chunk * 4);
        }
#pragma unroll
        for (int h = 0; h < 2; ++h) {
            int t = wv * 2 + h;
            int gn = nb0 + t * 16 + b_row;
            async_copy16(&Bsh[t * 512], Bh + (size_t)gn * K + k0 + b_chunk * 8);
        }
        __syncthreads();

        s16x8 a[4], b4[4];
#pragma unroll
        for (int i = 0; i < 4; ++i) {
            const float* p = &Asf[(m0 + i * 16 + col) * 32];
            float4 f0 = *(const float4*)(p + swA0 * 4);
            float4 f1 = *(const float4*)(p + swA1 * 4);
            a[i] = trunc8(f0, f1);
        }
#pragma unroll
        for (int j = 0; j < 4; ++j)
            b4[j] = *(const s16x8*)&Bsh[(n0 + j * 16 + col) * 32 + swB * 8];
#pragma unroll
        for (int i = 0; i < 4; ++i)
#pragma unroll
            for (int j = 0; j < 4; ++j)
                acc[i][j] = __builtin_amdgcn_mfma_f32_16x16x32_bf16(a[i], b4[j], acc[i][j], 0, 0, 0);
        __syncthreads();
    }

    // C/D layout: col = lane&15, row = quad*4 + reg
#pragma unroll
    for (int i = 0; i < 4; ++i) {
        int gr0 = row0 + m0 + i * 16 + quad * 4;
#pragma unroll
        for (int j = 0; j < 4; ++j) {
            int gc = nb0 + n0 + j * 16 + col;
#pragma unroll
            for (int r = 0; r < 4; ++r) {
                int gr = gr0 + r;
                if (gr < M) Cb[(size_t)gr * N + gc] = bf16_rne(acc[i][j][r]);
            }
        }
    }
}

// ---------------------------------------------------------------------------
// GEMM2: A bf16 [M][K], B 2-term bf16 hi/lo [N][K], N=128 single tile.
// Tile 64x128, BK=32, XOR-swizzled LDS as above.
// ---------------------------------------------------------------------------
__global__ __launch_bounds__(256) void gemm2_kernel(
    const unsigned short* __restrict__ A, const unsigned short* __restrict__ Bh,
    const unsigned short* __restrict__ Bl, unsigned short* __restrict__ Cb,
    int M, int N, int K) {
    __shared__ unsigned short Ash[64 * 32];    // 4 KB
    __shared__ unsigned short Bsh[128 * 32];   // 8 KB
    __shared__ unsigned short Bsl[128 * 32];   // 8 KB

    const int tid = threadIdx.x;
    const int lane = tid & 63;
    const int wv = tid >> 6;
    const int row0 = blockIdx.x * 64;
    const int col = lane & 15;
    const int quad = lane >> 4;
    const int m0 = (wv >> 1) * 32;
    const int n0 = (wv & 1) * 64;
    const int b_row = lane >> 2;
    const int b_chunk = (lane & 3) ^ ((lane >> 3) & 3);

    fx4 acc[2][4];
#pragma unroll
    for (int i = 0; i < 2; ++i)
#pragma unroll
        for (int j = 0; j < 4; ++j) acc[i][j] = (fx4){0.f, 0.f, 0.f, 0.f};

    const int swB = quad ^ ((col >> 1) & 3);

    for (int k0 = 0; k0 < K; k0 += 32) {
        {   // A: 1 instr per wave (16 rows x 64B)
            int gr = row0 + wv * 16 + b_row;
            if (gr >= M) gr = M - 1;
            async_copy16(&Ash[wv * 512], A + (size_t)gr * K + k0 + b_chunk * 8);
        }
#pragma unroll
        for (int h = 0; h < 2; ++h) {
            int t = wv * 2 + h;
            int gn = t * 16 + b_row;
            size_t go = (size_t)gn * K + k0 + b_chunk * 8;
            async_copy16(&Bsh[t * 512], Bh + go);
            async_copy16(&Bsl[t * 512], Bl + go);
        }
        __syncthreads();

        s16x8 a[2], bh4[4], bl4[4];
#pragma unroll
        for (int i = 0; i < 2; ++i)
            a[i] = *(const s16x8*)&Ash[(m0 + i * 16 + col) * 32 + swB * 8];
#pragma unroll
        for (int j = 0; j < 4; ++j) {
            int rb = (n0 + j * 16 + col) * 32 + swB * 8;
            bh4[j] = *(const s16x8*)&Bsh[rb];
            bl4[j] = *(const s16x8*)&Bsl[rb];
        }
#pragma unroll
        for (int i = 0; i < 2; ++i)
#pragma unroll
            for (int j = 0; j < 4; ++j) {
                acc[i][j] = __builtin_amdgcn_mfma_f32_16x16x32_bf16(a[i], bl4[j], acc[i][j], 0, 0, 0);
                acc[i][j] = __builtin_amdgcn_mfma_f32_16x16x32_bf16(a[i], bh4[j], acc[i][j], 0, 0, 0);
            }
        __syncthreads();
    }

#pragma unroll
    for (int i = 0; i < 2; ++i) {
        int gr0 = row0 + m0 + i * 16 + quad * 4;
#pragma unroll
        for (int j = 0; j < 4; ++j) {
            int gc = n0 + j * 16 + col;
#pragma unroll
            for (int r = 0; r < 4; ++r) {
                int gr = gr0 + r;
                if (gr < M) Cb[(size_t)gr * N + gc] = bf16_rne(acc[i][j][r]);
            }
        }
    }
}

// ---------------------------------------------------------------------------
// Per-(node,head) alignment dots, bf16 feature input
// ---------------------------------------------------------------------------
template <int H, int C>
__global__ void alsd_kernel(const unsigned short* __restrict__ hlin,
                            const float* __restrict__ a_s,
                            const float* __restrict__ a_d, float* __restrict__ als,
                            float* __restrict__ ald, int n) {
    int t = blockIdx.x * blockDim.x + threadIdx.x;
    if (t >= n * H) return;
    int node = t / H, h = t % H;
    const unsigned short* row = hlin + (size_t)node * H * C + h * C;
    const float* asr = a_s + h * C;
    const float* adr = a_d + h * C;
    float ss = 0.f, sd = 0.f;
#pragma unroll
    for (int c0 = 0; c0 < C; c0 += 4) {
        ushort4 u = *(const ushort4*)&row[c0];
        float v0 = bf16_to_f32(u.x), v1 = bf16_to_f32(u.y);
        float v2 = bf16_to_f32(u.z), v3 = bf16_to_f32(u.w);
        ss += v0 * asr[c0] + v1 * asr[c0 + 1] + v2 * asr[c0 + 2] + v3 * asr[c0 + 3];
        sd += v0 * adr[c0] + v1 * adr[c0 + 1] + v2 * adr[c0 + 2] + v3 * adr[c0 + 3];
    }
    als[t] = ss;
    ald[t] = sd;
}

// ---------------------------------------------------------------------------
// Fused attention-softmax + aggregation + bias + ReLU + BN, bf16 gather.
// ---------------------------------------------------------------------------
template <int F, int VEC, bool SPLIT>
__global__ __launch_bounds__(128) void agg_fused_kernel(
    const unsigned short* __restrict__ hlin, const float* __restrict__ als,
    const float* __restrict__ ald, const int* __restrict__ row_ptr,
    const int* __restrict__ csr_src, const float* __restrict__ bias,
    const float* __restrict__ gamma, const float* __restrict__ beta,
    const float* __restrict__ mean, const float* __restrict__ var,
    float* __restrict__ outf, unsigned short* __restrict__ outh) {
    int dst = blockIdx.x;
    int tid = threadIdx.x;
    int f0 = tid * VEC;
    int h = tid >> 4;              // (512,VEC4,C64) and (128,VEC1,C16)
    __shared__ float exs[16][8];
    __shared__ int srcs[16];
    int s0 = row_ptr[dst], s1 = row_ptr[dst + 1];
    int cj = tid >> 3, ch = tid & 7;
    float ald_c = ald[dst * HEADS + ch];
    float acc[VEC];
#pragma unroll
    for (int v = 0; v < VEC; ++v) acc[v] = 0.f;
    float den = 0.f;

    for (int base = s0; base < s1; base += 16) {
        int take = min(16, s1 - base);
        if (cj < take) {
            int src = csr_src[base + cj];
            if (ch == 0) srcs[cj] = src;
            float e = als[src * HEADS + ch] + ald_c;
            e = (e >= 0.f) ? e : NEG_SLOPE * e;
            exs[cj][ch] = __expf(e);
        }
        __syncthreads();
        for (int jj = 0; jj < take; ++jj) {
            int src = srcs[jj];
            float a = exs[jj][h];
            den += a;
            const unsigned short* rp = &hlin[(size_t)src * F + f0];
            if (VEC == 4) {
                ushort4 u = *(const ushort4*)rp;
                acc[0] += a * bf16_to_f32(u.x);
                acc[1] += a * bf16_to_f32(u.y);
                acc[2] += a * bf16_to_f32(u.z);
                acc[3] += a * bf16_to_f32(u.w);
            } else {
                acc[0] += a * bf16_to_f32(rp[0]);
            }
        }
        __syncthreads();
    }

    float rd = 1.f / (den + 1e-16f);
    float res[VEC];
#pragma unroll
    for (int v = 0; v < VEC; ++v) {
        int f = f0 + v;
        float val = acc[v] * rd + bias[f];
        val = fmaxf(val, 0.f);
        val = (val - mean[f]) * rsqrtf(var[f] + BN_EPS) * gamma[f] + beta[f];
        res[v] = val;
    }
    if (SPLIT) {
        if (VEC == 4) {
            ushort4 o;
            o.x = bf16_rne(res[0]); o.y = bf16_rne(res[1]);
            o.z = bf16_rne(res[2]); o.w = bf16_rne(res[3]);
            *(ushort4*)&outh[(size_t)dst * F + f0] = o;
        } else {
            outh[(size_t)dst * F + f0] = bf16_rne(res[0]);
        }
    } else {
        if (VEC == 4) {
            *(float4*)&outf[(size_t)dst * F + f0] =
                make_float4(res[0], res[1], res[2], res[3]);
        } else {
            outf[(size_t)dst * F + f0] = res[0];
        }
    }
}

// ---------------------------------------------------------------------------
// Layer 3 linear fused with alignment dots (fp32 input from agg2)
// ---------------------------------------------------------------------------
__global__ void layer3_lin_kernel(const float* __restrict__ h2, const float* __restrict__ W3,
                                  const float* __restrict__ as3, const float* __restrict__ ad3,
                                  float* __restrict__ h3lin, float* __restrict__ als,
                                  float* __restrict__ ald, int n) {
    int node = blockIdx.x * blockDim.x + threadIdx.x;
    if (node >= n) return;
    const float* row = h2 + (size_t)node * MID;
    float acc[OUTC] = {0.f, 0.f, 0.f, 0.f, 0.f};
    for (int k = 0; k < MID; ++k) {
        float x = row[k];
#pragma unroll
        for (int c = 0; c < OUTC; ++c) acc[c] += x * W3[k * OUTC + c];
    }
    float ss = 0.f, sd = 0.f;
#pragma unroll
    for (int c = 0; c < OUTC; ++c) {
        h3lin[(size_t)node * OUTC + c] = acc[c];
        ss += acc[c] * as3[c];
        sd += acc[c] * ad3[c];
    }
    als[node] = ss;
    ald[node] = sd;
}

// ---------------------------------------------------------------------------
// Layer 3: fused single-pass softmax + aggregation + bias + log_softmax
// ---------------------------------------------------------------------------
__global__ void agg3_lsm_kernel(const float* __restrict__ h3lin, const float* __restrict__ als,
                                const float* __restrict__ ald, const int* __restrict__ row_ptr,
                                const int* __restrict__ csr_src, const float* __restrict__ b3,
                                float* __restrict__ out, int n) {
    int dst = blockIdx.x * blockDim.x + threadIdx.x;
    if (dst >= n) return;
    int s0 = row_ptr[dst], s1 = row_ptr[dst + 1];
    float ad = ald[dst];
    float den = 0.f;
    float acc[OUTC] = {0.f, 0.f, 0.f, 0.f, 0.f};
    for (int j = s0; j < s1; ++j) {
        int src = csr_src[j];
        float e = als[src] + ad;
        e = (e >= 0.f) ? e : NEG_SLOPE * e;
        float x = __expf(e);
        den += x;
#pragma unroll
        for (int c = 0; c < OUTC; ++c) acc[c] += x * h3lin[(size_t)src * OUTC + c];
    }
    float rd = 1.f / (den + 1e-16f);
    float m = -INFINITY;
#pragma unroll
    for (int c = 0; c < OUTC; ++c) {
        acc[c] = acc[c] * rd + b3[c];
        m = fmaxf(m, acc[c]);
    }
    float s = 0.f;
#pragma unroll
    for (int c = 0; c < OUTC; ++c) s += __expf(acc[c] - m);
    float lse = m + __logf(s);
#pragma unroll
    for (int c = 0; c < OUTC; ++c) out[(size_t)dst * OUTC + c] = acc[c] - lse;
}

// ---------------------------------------------------------------------------
extern "C" void kernel_launch(void* const* d_in, const int* in_sizes, int n_in,
                              void* d_out, int out_size, void* d_ws, size_t ws_size,
                              hipStream_t stream) {
    const float* x   = (const float*)d_in[0];
    const int*   ei  = (const int*)d_in[1];
    const float* W1  = (const float*)d_in[2];
    const float* as1 = (const float*)d_in[3];
    const float* ad1 = (const float*)d_in[4];
    const float* b1  = (const float*)d_in[5];
    const float* W2  = (const float*)d_in[6];
    const float* as2 = (const float*)d_in[7];
    const float* ad2 = (const float*)d_in[8];
    const float* b2  = (const float*)d_in[9];
    const float* W3  = (const float*)d_in[10];
    const float* as3 = (const float*)d_in[11];
    const float* ad3 = (const float*)d_in[12];
    const float* b3  = (const float*)d_in[13];
    const float* g1  = (const float*)d_in[14];
    const float* be1 = (const float*)d_in[15];
    const float* m1  = (const float*)d_in[16];
    const float* v1  = (const float*)d_in[17];
    const float* g2  = (const float*)d_in[18];
    const float* be2 = (const float*)d_in[19];
    const float* m2  = (const float*)d_in[20];
    const float* v2  = (const float*)d_in[21];

    const int N = in_sizes[0] / IN_DIM;       // 20000
    const int E = in_sizes[1] / 2;            // 320000
    const int ET = E + N;
    const int MBLK1 = (N + 127) / 128;        // 157
    const int MBLK2 = (N + 63) / 64;          // 313

    char* ws = (char*)d_ws;
    size_t off = 0;
    auto take = [&](size_t bytes) -> char* {
        char* p = ws + off;
        off += (bytes + 255) & ~(size_t)255;
        return p;
    };
    int* deg      = (int*)take((size_t)N * 4);
    int* row_ptr  = (int*)take((size_t)(N + 1) * 4);
    int* cursor   = (int*)take((size_t)N * 4);
    int* csr_src  = (int*)take((size_t)ET * 4);
    unsigned short* W1h = (unsigned short*)take((size_t)HID * IN_DIM * 2);
    unsigned short* W2h = (unsigned short*)take((size_t)MID * HID * 2);
    unsigned short* W2l = (unsigned short*)take((size_t)MID * HID * 2);
    unsigned short* h1lin = (unsigned short*)take((size_t)N * HID * 2);   // bf16
    unsigned short* h1h   = (unsigned short*)take((size_t)N * HID * 2);   // bf16
    unsigned short* h2lin = (unsigned short*)take((size_t)N * MID * 2);   // bf16
    float* h2post = (float*)take((size_t)N * MID * 4);
    float* h3lin  = (float*)take((size_t)N * OUTC * 4);
    float* als    = (float*)take((size_t)N * HEADS * 4);
    float* ald    = (float*)take((size_t)N * HEADS * 4);

    // ---- CSR build + weight prep ----
    hipMemsetAsync(deg, 0, (size_t)N * 4, stream);
    hist_kernel<<<(ET + 255) / 256, 256, 0, stream>>>(ei, deg, ET, E);
    scan_kernel<<<1, 1024, 0, stream>>>(deg, row_ptr, cursor, N);
    scatter_kernel<<<(ET + 255) / 256, 256, 0, stream>>>(ei, cursor, csr_src, ET, E);
    transpose_split<false><<<dim3(HID / 32, IN_DIM / 32), 256, 0, stream>>>(
        W1, W1h, nullptr, IN_DIM, HID);
    transpose_split<true><<<dim3(MID / 32, HID / 32), 256, 0, stream>>>(
        W2, W2h, W2l, HID, MID);

    // ---- Layer 1: 1536 -> 8x64, ReLU, BN ----
    gemm1_kernel<<<640, 256, 0, stream>>>(x, W1h, h1lin, N, HID, IN_DIM, MBLK1);
    alsd_kernel<HEADS, 64><<<(N * HEADS + 255) / 256, 256, 0, stream>>>(h1lin, as1, ad1, als, ald, N);
    agg_fused_kernel<HID, 4, true><<<N, 128, 0, stream>>>(
        h1lin, als, ald, row_ptr, csr_src, b1, g1, be1, m1, v1, nullptr, h1h);

    // ---- Layer 2: 512 -> 8x16, ReLU, BN ----
    gemm2_kernel<<<MBLK2, 256, 0, stream>>>(h1h, W2h, W2l, h2lin, N, MID, HID);
    alsd_kernel<HEADS, 16><<<(N * HEADS + 255) / 256, 256, 0, stream>>>(h2lin, as2, ad2, als, ald, N);
    agg_fused_kernel<MID, 1, false><<<N, 128, 0, stream>>>(
        h2lin, als, ald, row_ptr, csr_src, b2, g2, be2, m2, v2, h2post, nullptr);

    // ---- Layer 3: 128 -> 1x5, log_softmax ----
    layer3_lin_kernel<<<(N + 255) / 256, 256, 0, stream>>>(
        h2post, W3, as3, ad3, h3lin, als, ald, N);
    agg3_lsm_kernel<<<(N + 255) / 256, 256, 0, stream>>>(
        h3lin, als, ald, row_ptr, csr_src, b3, (float*)d_out, N);
}